// Round 4
// baseline (429.799 us; speedup 1.0000x reference)
//
#include <hip/hip_runtime.h>
#include <hip/hip_bf16.h>
#include <cstdint>

#define HID 64
#define NHEADS 4
#define NEG_SLOPE 0.2f

// ---------------- CSR build ----------------
__global__ void histo_kernel(const int* __restrict__ dst, int* __restrict__ counts, int E) {
    int i = blockIdx.x * blockDim.x + threadIdx.x;
    if (i < E) atomicAdd(&counts[dst[i]], 1);
}

__global__ void scan_kernel(const int* __restrict__ counts, int* __restrict__ offs,
                            int* __restrict__ wp, int n) {
    __shared__ int partial[256];
    const int t = threadIdx.x;
    const int chunk = (n + 255) / 256;
    const int lo = t * chunk;
    const int hi = min(lo + chunk, n);
    int s = 0;
    for (int i = lo; i < hi; ++i) s += counts[i];
    partial[t] = s;
    __syncthreads();
    for (int o = 1; o < 256; o <<= 1) {
        int v = (t >= o) ? partial[t - o] : 0;
        __syncthreads();
        partial[t] += v;
        __syncthreads();
    }
    int run = partial[t] - s;
    for (int i = lo; i < hi; ++i) {
        offs[i] = run;
        wp[i] = run;
        run += counts[i];
    }
    if (t == 255) offs[n] = partial[255];
}

__global__ void scatter_kernel(const int* __restrict__ src, const int* __restrict__ dst,
                               int* __restrict__ wp, int* __restrict__ csr, int E) {
    int i = blockIdx.x * blockDim.x + threadIdx.x;
    if (i < E) {
        int d = dst[i];
        int p = atomicAdd(&wp[d], 1);
        csr[p] = src[i];
    }
}

// ---------------- GEMM: H[nrows,OUTC] = X[nrows,K] @ W[K,OUTC] ----------------
// 256 threads, BM x BN tile, thread tile TM x TN. TN=8 -> two float4 col groups
// at tx*4 and BN/2+tx*4 (16B lane stride: 2-way LDS aliasing = free).
// Pipelining: reg-prefetch of k+1 fragments + global-reg prefetch of next chunk.
template <int K, int OUTC, int BM, int BN, int TM, int TN>
__global__ __launch_bounds__(256) void gemm8_kernel(const float* __restrict__ X,
                                                    const float* __restrict__ W,
                                                    float* __restrict__ H, int nrows) {
    constexpr int KS = 32;
    constexpr int NG = TN / 4;                  // 1 or 2 col groups
    constexpr int THREADS = 256;
    constexpr int XJ = (KS * BM) / (4 * THREADS);
    constexpr int WJ = (KS * BN) / (4 * THREADS);
    static_assert((BM / TM) * (BN / TN) == THREADS, "geometry");

    __shared__ float xsT[KS][BM];  // xsT[k][r]
    __shared__ float wsT[KS][BN];  // wsT[k][c]

    const int tid = threadIdx.x;
    const int tx = tid & 15;        // 16 col groups
    const int ty = tid >> 4;        // 16 row groups
    const int row0 = blockIdx.x * BM;
    const int c0 = blockIdx.y * BN;

    const int xr = tid % BM;
    const int xkq = (tid / BM) * (4 * XJ);
    const int xrow = row0 + xr;
    const bool xok = xrow < nrows;

    float acc[TM][TN];
#pragma unroll
    for (int i = 0; i < TM; ++i)
#pragma unroll
        for (int j = 0; j < TN; ++j) acc[i][j] = 0.f;

    // ---- prologue: stage chunk 0 ----
    {
#pragma unroll
        for (int j = 0; j < XJ; ++j) {
            const int k = xkq + j * 4;
            float4 v = make_float4(0.f, 0.f, 0.f, 0.f);
            if (xok) v = *reinterpret_cast<const float4*>(&X[(size_t)xrow * K + k]);
            xsT[k + 0][xr] = v.x;
            xsT[k + 1][xr] = v.y;
            xsT[k + 2][xr] = v.z;
            xsT[k + 3][xr] = v.w;
        }
#pragma unroll
        for (int j = 0; j < WJ; ++j) {
            const int fi = tid + j * THREADS;
            const int k = fi / (BN / 4);
            const int c = (fi % (BN / 4)) * 4;
            *reinterpret_cast<float4*>(&wsT[k][c]) =
                *reinterpret_cast<const float4*>(&W[(size_t)k * OUTC + c0 + c]);
        }
    }
    __syncthreads();

    constexpr int NC = K / KS;
    for (int c = 0; c < NC; ++c) {
        // ---- issue global prefetch of next chunk into registers ----
        float4 xp[XJ], wpf[WJ];
        if (c + 1 < NC) {
            const int kb = (c + 1) * KS;
#pragma unroll
            for (int j = 0; j < XJ; ++j) {
                const int k = kb + xkq + j * 4;
                xp[j] = make_float4(0.f, 0.f, 0.f, 0.f);
                if (xok) xp[j] = *reinterpret_cast<const float4*>(&X[(size_t)xrow * K + k]);
            }
#pragma unroll
            for (int j = 0; j < WJ; ++j) {
                const int fi = tid + j * THREADS;
                const int k = kb + fi / (BN / 4);
                const int cc = (fi % (BN / 4)) * 4;
                wpf[j] = *reinterpret_cast<const float4*>(&W[(size_t)k * OUTC + c0 + cc]);
            }
        }
        // ---- compute current chunk from LDS with k+1 register prefetch ----
        {
            float4 av = *reinterpret_cast<const float4*>(&xsT[0][ty * 4]);
            float4 b0 = *reinterpret_cast<const float4*>(&wsT[0][tx * 4]);
            float4 b1;
            if (NG == 2) b1 = *reinterpret_cast<const float4*>(&wsT[0][BN / 2 + tx * 4]);
#pragma unroll
            for (int k = 0; k < KS; ++k) {
                float4 an, bn0, bn1;
                if (k + 1 < KS) {
                    an = *reinterpret_cast<const float4*>(&xsT[k + 1][ty * 4]);
                    bn0 = *reinterpret_cast<const float4*>(&wsT[k + 1][tx * 4]);
                    if (NG == 2)
                        bn1 = *reinterpret_cast<const float4*>(&wsT[k + 1][BN / 2 + tx * 4]);
                }
                const float avf[4] = {av.x, av.y, av.z, av.w};
                const float bvf0[4] = {b0.x, b0.y, b0.z, b0.w};
#pragma unroll
                for (int i = 0; i < TM; ++i)
#pragma unroll
                    for (int j = 0; j < 4; ++j)
                        acc[i][j] = fmaf(avf[i], bvf0[j], acc[i][j]);
                if (NG == 2) {
                    const float bvf1[4] = {b1.x, b1.y, b1.z, b1.w};
#pragma unroll
                    for (int i = 0; i < TM; ++i)
#pragma unroll
                        for (int j = 0; j < 4; ++j)
                            acc[i][4 + j] = fmaf(avf[i], bvf1[j], acc[i][4 + j]);
                }
                if (k + 1 < KS) {
                    av = an;
                    b0 = bn0;
                    if (NG == 2) b1 = bn1;
                }
            }
        }
        __syncthreads();
        // ---- write prefetched regs to LDS ----
        if (c + 1 < NC) {
#pragma unroll
            for (int j = 0; j < XJ; ++j) {
                const int k = xkq + j * 4;
                xsT[k + 0][xr] = xp[j].x;
                xsT[k + 1][xr] = xp[j].y;
                xsT[k + 2][xr] = xp[j].z;
                xsT[k + 3][xr] = xp[j].w;
            }
#pragma unroll
            for (int j = 0; j < WJ; ++j) {
                const int fi = tid + j * THREADS;
                const int k = fi / (BN / 4);
                const int cc = (fi % (BN / 4)) * 4;
                *reinterpret_cast<float4*>(&wsT[k][cc]) = wpf[j];
            }
        }
        __syncthreads();
    }

    // ---- epilogue ----
#pragma unroll
    for (int i = 0; i < TM; ++i) {
        const int row = row0 + ty * TM + i;
        if (row < nrows) {
            float4 v0 = make_float4(acc[i][0], acc[i][1], acc[i][2], acc[i][3]);
            *reinterpret_cast<float4*>(&H[(size_t)row * OUTC + c0 + tx * 4]) = v0;
            if (NG == 2) {
                float4 v1 = make_float4(acc[i][4], acc[i][5], acc[i][6], acc[i][7]);
                *reinterpret_cast<float4*>(&H[(size_t)row * OUTC + c0 + BN / 2 + tx * 4]) = v1;
            }
        }
    }
}

// ---------------- per-node attention logits ----------------
__global__ void alpha_kernel(const float* __restrict__ h, const float* __restrict__ a_s,
                             const float* __restrict__ a_d, float* __restrict__ alpha_s,
                             float* __restrict__ alpha_d, int n_nodes, int heads) {
    const int gw = (blockIdx.x * blockDim.x + threadIdx.x) >> 6;
    const int lane = threadIdx.x & 63;
    const int total = n_nodes * heads;
    if (gw >= total) return;
    const int n = gw / heads;
    const int hd = gw - n * heads;
    const float v = h[(size_t)n * heads * 64 + hd * 64 + lane];
    float vs = v * a_s[hd * 64 + lane];
    float vd = v * a_d[hd * 64 + lane];
#pragma unroll
    for (int o = 32; o; o >>= 1) {
        vs += __shfl_xor(vs, o);
        vd += __shfl_xor(vd, o);
    }
    if (lane == 0) {
        alpha_s[gw] = vs;
        alpha_d[gw] = vd;
    }
}

__device__ __forceinline__ float leaky(float e) {
    return (e > 0.f) ? e : NEG_SLOPE * e;
}

// ---------------- segment softmax -> per-edge weights (CSR order) ----------------
template <int H>
__global__ __launch_bounds__(256) void maxsumw_kernel(const float* __restrict__ alpha_s,
                                                      const float* __restrict__ alpha_d,
                                                      const int* __restrict__ offs,
                                                      const int* __restrict__ csr,
                                                      float* __restrict__ w, int n_nodes) {
    const int n = (blockIdx.x * blockDim.x + threadIdx.x) >> 6;
    const int lane = threadIdx.x & 63;
    if (n >= n_nodes) return;
    const int start = offs[n];
    const int end = offs[n + 1];

    float ad[H], m[H], sum[H];
#pragma unroll
    for (int h = 0; h < H; ++h) {
        ad[h] = alpha_d[n * H + h];
        m[h] = -INFINITY;
        sum[h] = 0.f;
    }
    for (int i = start + lane; i < end; i += 64) {
        const int s = csr[i];
#pragma unroll
        for (int h = 0; h < H; ++h) m[h] = fmaxf(m[h], leaky(alpha_s[s * H + h] + ad[h]));
    }
#pragma unroll
    for (int o = 32; o; o >>= 1)
#pragma unroll
        for (int h = 0; h < H; ++h) m[h] = fmaxf(m[h], __shfl_xor(m[h], o));
    for (int i = start + lane; i < end; i += 64) {
        const int s = csr[i];
        float ex[H];
#pragma unroll
        for (int h = 0; h < H; ++h) {
            ex[h] = __expf(leaky(alpha_s[s * H + h] + ad[h]) - m[h]);
            sum[h] += ex[h];
        }
        if (H == 4) {
            float4 v = make_float4(ex[0], ex[1], ex[2], ex[3]);
            *reinterpret_cast<float4*>(&w[(size_t)i * 4]) = v;
        } else {
            w[i] = ex[0];
        }
    }
#pragma unroll
    for (int o = 32; o; o >>= 1)
#pragma unroll
        for (int h = 0; h < H; ++h) sum[h] += __shfl_xor(sum[h], o);
    float recip[H];
#pragma unroll
    for (int h = 0; h < H; ++h) recip[h] = 1.f / (sum[h] + 1e-16f);
    for (int i = start + lane; i < end; i += 64) {
        if (H == 4) {
            float4 v = *reinterpret_cast<float4*>(&w[(size_t)i * 4]);
            v.x *= recip[0];
            v.y *= recip[1];
            v.z *= recip[2];
            v.w *= recip[3];
            *reinterpret_cast<float4*>(&w[(size_t)i * 4]) = v;
        } else {
            w[i] *= recip[0];
        }
    }
}

// ---------------- aggregation: weighted gather-sum ----------------
template <int H, bool RELU>
__global__ __launch_bounds__(256) void agg2_kernel(const float* __restrict__ h,
                                                   const float* __restrict__ w,
                                                   const int* __restrict__ offs,
                                                   const int* __restrict__ csr,
                                                   const float* __restrict__ bias,
                                                   float* __restrict__ out, int n_nodes) {
    int n, hd;
    if (H == 4) {
        n = blockIdx.x;
        hd = threadIdx.x >> 6;
    } else {
        n = blockIdx.x * 4 + (threadIdx.x >> 6);
        hd = 0;
    }
    const int c = threadIdx.x & 63;
    if (n >= n_nodes) return;
    const int start = offs[n];
    const int end = offs[n + 1];

    float acc0 = 0.f, acc1 = 0.f;
    int i = start;
    for (; i + 1 < end; i += 2) {
        const int s0 = csr[i];
        const int s1 = csr[i + 1];
        const float w0 = w[(size_t)i * H + hd];
        const float w1 = w[(size_t)(i + 1) * H + hd];
        acc0 = fmaf(w0, h[(size_t)s0 * (H * 64) + hd * 64 + c], acc0);
        acc1 = fmaf(w1, h[(size_t)s1 * (H * 64) + hd * 64 + c], acc1);
    }
    if (i < end) {
        const int s0 = csr[i];
        const float w0 = w[(size_t)i * H + hd];
        acc0 = fmaf(w0, h[(size_t)s0 * (H * 64) + hd * 64 + c], acc0);
    }
    float o = acc0 + acc1 + bias[hd * 64 + c];
    if (RELU) o = fmaxf(o, 0.f);
    out[(size_t)n * (H * 64) + hd * 64 + c] = o;
}

// ---------------- launch ----------------
extern "C" void kernel_launch(void* const* d_in, const int* in_sizes, int n_in,
                              void* d_out, int out_size, void* d_ws, size_t ws_size,
                              hipStream_t stream) {
    const float* x   = (const float*)d_in[0];
    const int*   ei  = (const int*)d_in[1];
    const float* W1  = (const float*)d_in[2];
    const float* a1s = (const float*)d_in[3];
    const float* a1d = (const float*)d_in[4];
    const float* b1  = (const float*)d_in[5];
    const float* W2  = (const float*)d_in[6];
    const float* a2s = (const float*)d_in[7];
    const float* a2d = (const float*)d_in[8];
    const float* b2  = (const float*)d_in[9];
    const float* W3  = (const float*)d_in[10];
    const float* a3s = (const float*)d_in[11];
    const float* a3d = (const float*)d_in[12];
    const float* b3  = (const float*)d_in[13];
    float* out = (float*)d_out;

    const int N = in_sizes[0] / HID;
    const int E = in_sizes[1] / 2;
    const int* src = ei;
    const int* dst = ei + E;

    char* p = (char*)d_ws;
    auto alloc = [&](size_t bytes) {
        char* q = p;
        p += (bytes + 255) & ~(size_t)255;
        return q;
    };
    float* bufA = (float*)alloc((size_t)N * 256 * 4);
    float* bufB = (float*)alloc((size_t)N * 256 * 4);
    float* alpS = (float*)alloc((size_t)N * NHEADS * 4);
    float* alpD = (float*)alloc((size_t)N * NHEADS * 4);
    float* wbuf = (float*)alloc((size_t)E * NHEADS * 4);
    int* counts = (int*)alloc((size_t)N * 4);
    int* offs   = (int*)alloc((size_t)(N + 1) * 4);
    int* wp     = (int*)alloc((size_t)N * 4);
    int* csr    = (int*)alloc((size_t)E * 4);

    hipMemsetAsync(counts, 0, (size_t)N * 4, stream);
    const int eb = (E + 255) / 256;
    histo_kernel<<<eb, 256, 0, stream>>>(dst, counts, E);
    scan_kernel<<<1, 256, 0, stream>>>(counts, offs, wp, N);
    scatter_kernel<<<eb, 256, 0, stream>>>(src, dst, wp, csr, E);

    const int gb64 = (N + 63) / 64;
    const int nwb = (N * 64 + 255) / 256;

    // layer 1: x[N,64] @ W1[64,256]
    gemm8_kernel<64, 256, 64, 128, 4, 8><<<dim3(gb64, 2), 256, 0, stream>>>(x, W1, bufA, N);
    alpha_kernel<<<(N * NHEADS * 64 + 255) / 256, 256, 0, stream>>>(bufA, a1s, a1d, alpS, alpD, N, NHEADS);
    maxsumw_kernel<NHEADS><<<nwb, 256, 0, stream>>>(alpS, alpD, offs, csr, wbuf, N);
    agg2_kernel<NHEADS, true><<<N, 256, 0, stream>>>(bufA, wbuf, offs, csr, b1, bufB, N);

    // layer 2: bufB[N,256] @ W2[256,256]
    gemm8_kernel<256, 256, 64, 128, 4, 8><<<dim3(gb64, 2), 256, 0, stream>>>(bufB, W2, bufA, N);
    alpha_kernel<<<(N * NHEADS * 64 + 255) / 256, 256, 0, stream>>>(bufA, a2s, a2d, alpS, alpD, N, NHEADS);
    maxsumw_kernel<NHEADS><<<nwb, 256, 0, stream>>>(alpS, alpD, offs, csr, wbuf, N);
    agg2_kernel<NHEADS, true><<<N, 256, 0, stream>>>(bufA, wbuf, offs, csr, b2, bufB, N);

    // layer 3: bufB[N,256] @ W3[256,64]
    gemm8_kernel<256, 64, 64, 64, 4, 4><<<dim3(gb64, 1), 256, 0, stream>>>(bufB, W3, bufA, N);
    alpha_kernel<<<(N * 1 * 64 + 255) / 256, 256, 0, stream>>>(bufA, a3s, a3d, alpS, alpD, N, 1);
    maxsumw_kernel<1><<<nwb, 256, 0, stream>>>(alpS, alpD, offs, csr, wbuf, N);
    agg2_kernel<1, false><<<(N + 3) / 4, 256, 0, stream>>>(bufA, wbuf, offs, csr, b3, out, N);
}

// Round 5
// 336.124 us; speedup vs baseline: 1.2787x; 1.2787x over previous
//
#include <hip/hip_runtime.h>
#include <hip/hip_bf16.h>
#include <cstdint>

#define HID 64
#define NHEADS 4
#define NEG_SLOPE 0.2f

typedef __attribute__((ext_vector_type(8))) short short8;
typedef __attribute__((ext_vector_type(16))) float f32x16;

__device__ __forceinline__ unsigned short f2bf(float f) {
    unsigned int u = __float_as_uint(f);
    unsigned int r = (u + 0x7FFFu + ((u >> 16) & 1u)) >> 16;
    return (unsigned short)r;
}
__device__ __forceinline__ float bf2f(unsigned short h) {
    return __uint_as_float(((unsigned int)h) << 16);
}

// ---------------- CSR build ----------------
__global__ void histo_kernel(const int* __restrict__ dst, int* __restrict__ counts, int E) {
    int i = blockIdx.x * blockDim.x + threadIdx.x;
    if (i < E) atomicAdd(&counts[dst[i]], 1);
}

__global__ void scan_kernel(const int* __restrict__ counts, int* __restrict__ offs,
                            int* __restrict__ wp, int n) {
    __shared__ int partial[256];
    const int t = threadIdx.x;
    const int chunk = (n + 255) / 256;
    const int lo = t * chunk;
    const int hi = min(lo + chunk, n);
    int s = 0;
    for (int i = lo; i < hi; ++i) s += counts[i];
    partial[t] = s;
    __syncthreads();
    for (int o = 1; o < 256; o <<= 1) {
        int v = (t >= o) ? partial[t - o] : 0;
        __syncthreads();
        partial[t] += v;
        __syncthreads();
    }
    int run = partial[t] - s;
    for (int i = lo; i < hi; ++i) {
        offs[i] = run;
        wp[i] = run;
        run += counts[i];
    }
    if (t == 255) offs[n] = partial[255];
}

__global__ void scatter_kernel(const int* __restrict__ src, const int* __restrict__ dst,
                               int* __restrict__ wp, int* __restrict__ csr, int E) {
    int i = blockIdx.x * blockDim.x + threadIdx.x;
    if (i < E) {
        int d = dst[i];
        int p = atomicAdd(&wp[d], 1);
        csr[p] = src[i];
    }
}

// ---------------- W pre-split: WT_hi/WT_lo[c][k] bf16 from W[k][c] fp32 ----------------
__global__ void wsplit_kernel(const float* __restrict__ W, unsigned short* __restrict__ WTh,
                              unsigned short* __restrict__ WTl, int K, int OUTC) {
    int i = blockIdx.x * blockDim.x + threadIdx.x;
    if (i >= K * OUTC) return;
    int c = i / K;
    int k = i - c * K;
    float v = W[(size_t)k * OUTC + c];
    unsigned short h = f2bf(v);
    WTh[i] = h;
    WTl[i] = f2bf(v - bf2f(h));
}

// ---------------- GEMM via MFMA split-bf16 ----------------
// H[nrows,OUTC] = X[nrows,K] @ W[K,OUTC], fp32 in/out, bf16 hi/lo internally.
// Block: 256 thr = 4 waves (2 row groups x 2 col groups). Block tile 64 x BN.
// Wave tile: 32 x (BN/2). mfma_f32_32x32x16_bf16; K-chunk 32.
// LDS layout [row][k] bf16 with 16B-block XOR swizzle: blk ^= (row & 3).
template <int K, int OUTC, int BN>
__global__ __launch_bounds__(256) void gemm_mfma_kernel(const float* __restrict__ X,
                                                        const unsigned short* __restrict__ WTh,
                                                        const unsigned short* __restrict__ WTl,
                                                        float* __restrict__ H, int nrows) {
    constexpr int CGS = BN / 64;           // 32-col mfma tiles per wave (1 or 2)
    constexpr int NB = BN / 64;            // 16B k-blocks per thread per B array
    constexpr int TPC = 4 / NB;            // threads per B column
    __shared__ short Ah[64 * 32];
    __shared__ short Al[64 * 32];
    __shared__ short Bh[BN * 32];
    __shared__ short Bl[BN * 32];

    const int tid = threadIdx.x;
    const int lane = tid & 63;
    const int wid = tid >> 6;
    const int wr = wid >> 1;               // wave row group (0/1)
    const int wc = wid & 1;                // wave col group (0/1)
    const int r31 = lane & 31;
    const int khw = lane >> 5;             // k half within 16
    const int row0 = blockIdx.x * 64;
    const int c0 = blockIdx.y * BN;

    // A staging mapping: 4 threads per row, 8 floats each
    const int ar = tid >> 2;
    const int akq = (tid & 3) * 8;
    const int arow = row0 + ar;
    const bool aok = arow < nrows;

    // B staging mapping
    const int bcol = tid / TPC;
    const int bkb = (tid % TPC) * NB;      // starting 16B k-block (8 shorts each)

    f32x16 acc[CGS];
#pragma unroll
    for (int cg = 0; cg < CGS; ++cg)
#pragma unroll
        for (int r = 0; r < 16; ++r) acc[cg][r] = 0.f;

    for (int k0 = 0; k0 < K; k0 += 32) {
        __syncthreads();
        // ---- stage A (convert fp32 -> hi/lo bf16) ----
        {
            float4 v0 = make_float4(0.f, 0.f, 0.f, 0.f), v1 = v0;
            if (aok) {
                v0 = *reinterpret_cast<const float4*>(&X[(size_t)arow * K + k0 + akq]);
                v1 = *reinterpret_cast<const float4*>(&X[(size_t)arow * K + k0 + akq + 4]);
            }
            float vs[8] = {v0.x, v0.y, v0.z, v0.w, v1.x, v1.y, v1.z, v1.w};
            short8 hi, lo;
#pragma unroll
            for (int j = 0; j < 8; ++j) {
                unsigned short h = f2bf(vs[j]);
                hi[j] = (short)h;
                lo[j] = (short)f2bf(vs[j] - bf2f(h));
            }
            const int blk = (akq >> 3) ^ (ar & 3);
            const int off = ar * 32 + (blk << 3);
            *reinterpret_cast<short8*>(&Ah[off]) = hi;
            *reinterpret_cast<short8*>(&Al[off]) = lo;
        }
        // ---- stage B (copy pre-split bf16) ----
        {
            const unsigned short* srcH = &WTh[(size_t)(c0 + bcol) * K + k0 + bkb * 8];
            const unsigned short* srcL = &WTl[(size_t)(c0 + bcol) * K + k0 + bkb * 8];
#pragma unroll
            for (int b = 0; b < NB; ++b) {
                short8 h = *reinterpret_cast<const short8*>(&srcH[b * 8]);
                short8 l = *reinterpret_cast<const short8*>(&srcL[b * 8]);
                const int blk = (bkb + b) ^ (bcol & 3);
                const int off = bcol * 32 + (blk << 3);
                *reinterpret_cast<short8*>(&Bh[off]) = h;
                *reinterpret_cast<short8*>(&Bl[off]) = l;
            }
        }
        __syncthreads();
        // ---- compute: 2 k-sub-steps of 16 ----
#pragma unroll
        for (int ks = 0; ks < 32; ks += 16) {
            const int kb = (ks >> 3) + khw;
            const int aoff = (wr * 32 + r31) * 32 + ((kb ^ (r31 & 3)) << 3);
            short8 ah = *reinterpret_cast<const short8*>(&Ah[aoff]);
            short8 al = *reinterpret_cast<const short8*>(&Al[aoff]);
#pragma unroll
            for (int cg = 0; cg < CGS; ++cg) {
                const int coll = wc * (BN / 2) + cg * 32 + r31;
                const int boff = coll * 32 + ((kb ^ (r31 & 3)) << 3);
                short8 bh = *reinterpret_cast<const short8*>(&Bh[boff]);
                short8 bl = *reinterpret_cast<const short8*>(&Bl[boff]);
                acc[cg] = __builtin_amdgcn_mfma_f32_32x32x16_bf16(ah, bh, acc[cg], 0, 0, 0);
                acc[cg] = __builtin_amdgcn_mfma_f32_32x32x16_bf16(ah, bl, acc[cg], 0, 0, 0);
                acc[cg] = __builtin_amdgcn_mfma_f32_32x32x16_bf16(al, bh, acc[cg], 0, 0, 0);
            }
        }
    }

    // ---- epilogue: C/D layout col=lane&31, row=(reg&3)+8*(reg>>2)+4*(lane>>5) ----
#pragma unroll
    for (int cg = 0; cg < CGS; ++cg) {
#pragma unroll
        for (int reg = 0; reg < 16; ++reg) {
            const int row = row0 + wr * 32 + (reg & 3) + 8 * (reg >> 2) + 4 * khw;
            if (row < nrows)
                H[(size_t)row * OUTC + c0 + wc * (BN / 2) + cg * 32 + r31] = acc[cg][reg];
        }
    }
}

// ---------------- per-node attention logits ----------------
__global__ void alpha_kernel(const float* __restrict__ h, const float* __restrict__ a_s,
                             const float* __restrict__ a_d, float* __restrict__ alpha_s,
                             float* __restrict__ alpha_d, int n_nodes, int heads) {
    const int gw = (blockIdx.x * blockDim.x + threadIdx.x) >> 6;
    const int lane = threadIdx.x & 63;
    const int total = n_nodes * heads;
    if (gw >= total) return;
    const int n = gw / heads;
    const int hd = gw - n * heads;
    const float v = h[(size_t)n * heads * 64 + hd * 64 + lane];
    float vs = v * a_s[hd * 64 + lane];
    float vd = v * a_d[hd * 64 + lane];
#pragma unroll
    for (int o = 32; o; o >>= 1) {
        vs += __shfl_xor(vs, o);
        vd += __shfl_xor(vd, o);
    }
    if (lane == 0) {
        alpha_s[gw] = vs;
        alpha_d[gw] = vd;
    }
}

__device__ __forceinline__ float leaky(float e) {
    return (e > 0.f) ? e : NEG_SLOPE * e;
}

// ---------------- segment softmax -> per-edge weights (CSR order) ----------------
template <int H>
__global__ __launch_bounds__(256) void maxsumw_kernel(const float* __restrict__ alpha_s,
                                                      const float* __restrict__ alpha_d,
                                                      const int* __restrict__ offs,
                                                      const int* __restrict__ csr,
                                                      float* __restrict__ w, int n_nodes) {
    const int n = (blockIdx.x * blockDim.x + threadIdx.x) >> 6;
    const int lane = threadIdx.x & 63;
    if (n >= n_nodes) return;
    const int start = offs[n];
    const int end = offs[n + 1];

    float ad[H], m[H], sum[H];
#pragma unroll
    for (int h = 0; h < H; ++h) {
        ad[h] = alpha_d[n * H + h];
        m[h] = -INFINITY;
        sum[h] = 0.f;
    }
    for (int i = start + lane; i < end; i += 64) {
        const int s = csr[i];
#pragma unroll
        for (int h = 0; h < H; ++h) m[h] = fmaxf(m[h], leaky(alpha_s[s * H + h] + ad[h]));
    }
#pragma unroll
    for (int o = 32; o; o >>= 1)
#pragma unroll
        for (int h = 0; h < H; ++h) m[h] = fmaxf(m[h], __shfl_xor(m[h], o));
    for (int i = start + lane; i < end; i += 64) {
        const int s = csr[i];
        float ex[H];
#pragma unroll
        for (int h = 0; h < H; ++h) {
            ex[h] = __expf(leaky(alpha_s[s * H + h] + ad[h]) - m[h]);
            sum[h] += ex[h];
        }
        if (H == 4) {
            float4 v = make_float4(ex[0], ex[1], ex[2], ex[3]);
            *reinterpret_cast<float4*>(&w[(size_t)i * 4]) = v;
        } else {
            w[i] = ex[0];
        }
    }
#pragma unroll
    for (int o = 32; o; o >>= 1)
#pragma unroll
        for (int h = 0; h < H; ++h) sum[h] += __shfl_xor(sum[h], o);
    float recip[H];
#pragma unroll
    for (int h = 0; h < H; ++h) recip[h] = 1.f / (sum[h] + 1e-16f);
    for (int i = start + lane; i < end; i += 64) {
        if (H == 4) {
            float4 v = *reinterpret_cast<float4*>(&w[(size_t)i * 4]);
            v.x *= recip[0];
            v.y *= recip[1];
            v.z *= recip[2];
            v.w *= recip[3];
            *reinterpret_cast<float4*>(&w[(size_t)i * 4]) = v;
        } else {
            w[i] *= recip[0];
        }
    }
}

// ---------------- aggregation: weighted gather-sum ----------------
template <int H, bool RELU>
__global__ __launch_bounds__(256) void agg2_kernel(const float* __restrict__ h,
                                                   const float* __restrict__ w,
                                                   const int* __restrict__ offs,
                                                   const int* __restrict__ csr,
                                                   const float* __restrict__ bias,
                                                   float* __restrict__ out, int n_nodes) {
    int n, hd;
    if (H == 4) {
        n = blockIdx.x;
        hd = threadIdx.x >> 6;
    } else {
        n = blockIdx.x * 4 + (threadIdx.x >> 6);
        hd = 0;
    }
    const int c = threadIdx.x & 63;
    if (n >= n_nodes) return;
    const int start = offs[n];
    const int end = offs[n + 1];

    float acc0 = 0.f, acc1 = 0.f;
    int i = start;
    for (; i + 1 < end; i += 2) {
        const int s0 = csr[i];
        const int s1 = csr[i + 1];
        const float w0 = w[(size_t)i * H + hd];
        const float w1 = w[(size_t)(i + 1) * H + hd];
        acc0 = fmaf(w0, h[(size_t)s0 * (H * 64) + hd * 64 + c], acc0);
        acc1 = fmaf(w1, h[(size_t)s1 * (H * 64) + hd * 64 + c], acc1);
    }
    if (i < end) {
        const int s0 = csr[i];
        const float w0 = w[(size_t)i * H + hd];
        acc0 = fmaf(w0, h[(size_t)s0 * (H * 64) + hd * 64 + c], acc0);
    }
    float o = acc0 + acc1 + bias[hd * 64 + c];
    if (RELU) o = fmaxf(o, 0.f);
    out[(size_t)n * (H * 64) + hd * 64 + c] = o;
}

// ---------------- launch ----------------
extern "C" void kernel_launch(void* const* d_in, const int* in_sizes, int n_in,
                              void* d_out, int out_size, void* d_ws, size_t ws_size,
                              hipStream_t stream) {
    const float* x   = (const float*)d_in[0];
    const int*   ei  = (const int*)d_in[1];
    const float* W1  = (const float*)d_in[2];
    const float* a1s = (const float*)d_in[3];
    const float* a1d = (const float*)d_in[4];
    const float* b1  = (const float*)d_in[5];
    const float* W2  = (const float*)d_in[6];
    const float* a2s = (const float*)d_in[7];
    const float* a2d = (const float*)d_in[8];
    const float* b2  = (const float*)d_in[9];
    const float* W3  = (const float*)d_in[10];
    const float* a3s = (const float*)d_in[11];
    const float* a3d = (const float*)d_in[12];
    const float* b3  = (const float*)d_in[13];
    float* out = (float*)d_out;

    const int N = in_sizes[0] / HID;
    const int E = in_sizes[1] / 2;
    const int* src = ei;
    const int* dst = ei + E;

    char* p = (char*)d_ws;
    auto alloc = [&](size_t bytes) {
        char* q = p;
        p += (bytes + 255) & ~(size_t)255;
        return q;
    };
    float* bufA = (float*)alloc((size_t)N * 256 * 4);
    float* bufB = (float*)alloc((size_t)N * 256 * 4);
    float* alpS = (float*)alloc((size_t)N * NHEADS * 4);
    float* alpD = (float*)alloc((size_t)N * NHEADS * 4);
    float* wbuf = (float*)alloc((size_t)E * NHEADS * 4);
    int* counts = (int*)alloc((size_t)N * 4);
    int* offs   = (int*)alloc((size_t)(N + 1) * 4);
    int* wp     = (int*)alloc((size_t)N * 4);
    int* csr    = (int*)alloc((size_t)E * 4);
    unsigned short* wt1h = (unsigned short*)alloc((size_t)64 * 256 * 2);
    unsigned short* wt1l = (unsigned short*)alloc((size_t)64 * 256 * 2);
    unsigned short* wt2h = (unsigned short*)alloc((size_t)256 * 256 * 2);
    unsigned short* wt2l = (unsigned short*)alloc((size_t)256 * 256 * 2);
    unsigned short* wt3h = (unsigned short*)alloc((size_t)256 * 64 * 2);
    unsigned short* wt3l = (unsigned short*)alloc((size_t)256 * 64 * 2);

    // W transpose+split (tiny)
    wsplit_kernel<<<(64 * 256 + 255) / 256, 256, 0, stream>>>(W1, wt1h, wt1l, 64, 256);
    wsplit_kernel<<<(256 * 256 + 255) / 256, 256, 0, stream>>>(W2, wt2h, wt2l, 256, 256);
    wsplit_kernel<<<(256 * 64 + 255) / 256, 256, 0, stream>>>(W3, wt3h, wt3l, 256, 64);

    hipMemsetAsync(counts, 0, (size_t)N * 4, stream);
    const int eb = (E + 255) / 256;
    histo_kernel<<<eb, 256, 0, stream>>>(dst, counts, E);
    scan_kernel<<<1, 256, 0, stream>>>(counts, offs, wp, N);
    scatter_kernel<<<eb, 256, 0, stream>>>(src, dst, wp, csr, E);

    const int gb64 = (N + 63) / 64;
    const int nwb = (N * 64 + 255) / 256;

    // layer 1: x[N,64] @ W1[64,256]
    gemm_mfma_kernel<64, 256, 128><<<dim3(gb64, 2), 256, 0, stream>>>(x, wt1h, wt1l, bufA, N);
    alpha_kernel<<<(N * NHEADS * 64 + 255) / 256, 256, 0, stream>>>(bufA, a1s, a1d, alpS, alpD, N, NHEADS);
    maxsumw_kernel<NHEADS><<<nwb, 256, 0, stream>>>(alpS, alpD, offs, csr, wbuf, N);
    agg2_kernel<NHEADS, true><<<N, 256, 0, stream>>>(bufA, wbuf, offs, csr, b1, bufB, N);

    // layer 2: bufB[N,256] @ W2[256,256]
    gemm_mfma_kernel<256, 256, 128><<<dim3(gb64, 2), 256, 0, stream>>>(bufB, wt2h, wt2l, bufA, N);
    alpha_kernel<<<(N * NHEADS * 64 + 255) / 256, 256, 0, stream>>>(bufA, a2s, a2d, alpS, alpD, N, NHEADS);
    maxsumw_kernel<NHEADS><<<nwb, 256, 0, stream>>>(alpS, alpD, offs, csr, wbuf, N);
    agg2_kernel<NHEADS, true><<<N, 256, 0, stream>>>(bufA, wbuf, offs, csr, b2, bufB, N);

    // layer 3: bufB[N,256] @ W3[256,64]
    gemm_mfma_kernel<256, 64, 64><<<dim3(gb64, 1), 256, 0, stream>>>(bufB, wt3h, wt3l, bufA, N);
    alpha_kernel<<<(N * 1 * 64 + 255) / 256, 256, 0, stream>>>(bufA, a3s, a3d, alpS, alpD, N, 1);
    maxsumw_kernel<1><<<nwb, 256, 0, stream>>>(alpS, alpD, offs, csr, wbuf, N);
    agg2_kernel<1, false><<<(N + 3) / 4, 256, 0, stream>>>(bufA, wbuf, offs, csr, b3, out, N);
}

// Round 6
// 314.277 us; speedup vs baseline: 1.3676x; 1.0695x over previous
//
#include <hip/hip_runtime.h>
#include <hip/hip_bf16.h>
#include <cstdint>

#define HID 64
#define NHEADS 4
#define NEG_SLOPE 0.2f

typedef __attribute__((ext_vector_type(8))) short short8;
typedef __attribute__((ext_vector_type(16))) float f32x16;

__device__ __forceinline__ unsigned short f2bf(float f) {
    unsigned int u = __float_as_uint(f);
    unsigned int r = (u + 0x7FFFu + ((u >> 16) & 1u)) >> 16;
    return (unsigned short)r;
}
__device__ __forceinline__ float bf2f(unsigned short h) {
    return __uint_as_float(((unsigned int)h) << 16);
}

// ---------------- CSR build ----------------
__global__ void histo_kernel(const int* __restrict__ dst, int* __restrict__ counts, int E) {
    int i = blockIdx.x * blockDim.x + threadIdx.x;
    if (i < E) atomicAdd(&counts[dst[i]], 1);
}

__global__ void scan_kernel(const int* __restrict__ counts, int* __restrict__ offs,
                            int* __restrict__ wp, int n) {
    __shared__ int partial[256];
    const int t = threadIdx.x;
    const int chunk = (n + 255) / 256;
    const int lo = t * chunk;
    const int hi = min(lo + chunk, n);
    int s = 0;
    for (int i = lo; i < hi; ++i) s += counts[i];
    partial[t] = s;
    __syncthreads();
    for (int o = 1; o < 256; o <<= 1) {
        int v = (t >= o) ? partial[t - o] : 0;
        __syncthreads();
        partial[t] += v;
        __syncthreads();
    }
    int run = partial[t] - s;
    for (int i = lo; i < hi; ++i) {
        offs[i] = run;
        wp[i] = run;
        run += counts[i];
    }
    if (t == 255) offs[n] = partial[255];
}

__global__ void scatter_kernel(const int* __restrict__ src, const int* __restrict__ dst,
                               int* __restrict__ wp, int* __restrict__ csr, int E) {
    int i = blockIdx.x * blockDim.x + threadIdx.x;
    if (i < E) {
        int d = dst[i];
        int p = atomicAdd(&wp[d], 1);
        csr[p] = src[i];
    }
}

// ---------------- W pre-split: WT_hi/WT_lo[c][k] bf16 from W[k][c] fp32 ----------------
__global__ void wsplit_kernel(const float* __restrict__ W, unsigned short* __restrict__ WTh,
                              unsigned short* __restrict__ WTl, int K, int OUTC) {
    int i = blockIdx.x * blockDim.x + threadIdx.x;
    if (i >= K * OUTC) return;
    int c = i / K;
    int k = i - c * K;
    float v = W[(size_t)k * OUTC + c];
    unsigned short h = f2bf(v);
    WTh[i] = h;
    WTl[i] = f2bf(v - bf2f(h));
}

// ---------------- GEMM via MFMA split-bf16 (unchanged from round 4) ----------------
template <int K, int OUTC, int BN>
__global__ __launch_bounds__(256) void gemm_mfma_kernel(const float* __restrict__ X,
                                                        const unsigned short* __restrict__ WTh,
                                                        const unsigned short* __restrict__ WTl,
                                                        float* __restrict__ H, int nrows) {
    constexpr int CGS = BN / 64;
    constexpr int NB = BN / 64;
    constexpr int TPC = 4 / NB;
    __shared__ short Ah[64 * 32];
    __shared__ short Al[64 * 32];
    __shared__ short Bh[BN * 32];
    __shared__ short Bl[BN * 32];

    const int tid = threadIdx.x;
    const int lane = tid & 63;
    const int wid = tid >> 6;
    const int wr = wid >> 1;
    const int wc = wid & 1;
    const int r31 = lane & 31;
    const int khw = lane >> 5;
    const int row0 = blockIdx.x * 64;
    const int c0 = blockIdx.y * BN;

    const int ar = tid >> 2;
    const int akq = (tid & 3) * 8;
    const int arow = row0 + ar;
    const bool aok = arow < nrows;

    const int bcol = tid / TPC;
    const int bkb = (tid % TPC) * NB;

    f32x16 acc[CGS];
#pragma unroll
    for (int cg = 0; cg < CGS; ++cg)
#pragma unroll
        for (int r = 0; r < 16; ++r) acc[cg][r] = 0.f;

    for (int k0 = 0; k0 < K; k0 += 32) {
        __syncthreads();
        {
            float4 v0 = make_float4(0.f, 0.f, 0.f, 0.f), v1 = v0;
            if (aok) {
                v0 = *reinterpret_cast<const float4*>(&X[(size_t)arow * K + k0 + akq]);
                v1 = *reinterpret_cast<const float4*>(&X[(size_t)arow * K + k0 + akq + 4]);
            }
            float vs[8] = {v0.x, v0.y, v0.z, v0.w, v1.x, v1.y, v1.z, v1.w};
            short8 hi, lo;
#pragma unroll
            for (int j = 0; j < 8; ++j) {
                unsigned short h = f2bf(vs[j]);
                hi[j] = (short)h;
                lo[j] = (short)f2bf(vs[j] - bf2f(h));
            }
            const int blk = (akq >> 3) ^ (ar & 3);
            const int off = ar * 32 + (blk << 3);
            *reinterpret_cast<short8*>(&Ah[off]) = hi;
            *reinterpret_cast<short8*>(&Al[off]) = lo;
        }
        {
            const unsigned short* srcH = &WTh[(size_t)(c0 + bcol) * K + k0 + bkb * 8];
            const unsigned short* srcL = &WTl[(size_t)(c0 + bcol) * K + k0 + bkb * 8];
#pragma unroll
            for (int b = 0; b < NB; ++b) {
                short8 h = *reinterpret_cast<const short8*>(&srcH[b * 8]);
                short8 l = *reinterpret_cast<const short8*>(&srcL[b * 8]);
                const int blk = (bkb + b) ^ (bcol & 3);
                const int off = bcol * 32 + (blk << 3);
                *reinterpret_cast<short8*>(&Bh[off]) = h;
                *reinterpret_cast<short8*>(&Bl[off]) = l;
            }
        }
        __syncthreads();
#pragma unroll
        for (int ks = 0; ks < 32; ks += 16) {
            const int kb = (ks >> 3) + khw;
            const int aoff = (wr * 32 + r31) * 32 + ((kb ^ (r31 & 3)) << 3);
            short8 ah = *reinterpret_cast<const short8*>(&Ah[aoff]);
            short8 al = *reinterpret_cast<const short8*>(&Al[aoff]);
#pragma unroll
            for (int cg = 0; cg < CGS; ++cg) {
                const int coll = wc * (BN / 2) + cg * 32 + r31;
                const int boff = coll * 32 + ((kb ^ (r31 & 3)) << 3);
                short8 bh = *reinterpret_cast<const short8*>(&Bh[boff]);
                short8 bl = *reinterpret_cast<const short8*>(&Bl[boff]);
                acc[cg] = __builtin_amdgcn_mfma_f32_32x32x16_bf16(ah, bh, acc[cg], 0, 0, 0);
                acc[cg] = __builtin_amdgcn_mfma_f32_32x32x16_bf16(ah, bl, acc[cg], 0, 0, 0);
                acc[cg] = __builtin_amdgcn_mfma_f32_32x32x16_bf16(al, bh, acc[cg], 0, 0, 0);
            }
        }
    }

#pragma unroll
    for (int cg = 0; cg < CGS; ++cg) {
#pragma unroll
        for (int reg = 0; reg < 16; ++reg) {
            const int row = row0 + wr * 32 + (reg & 3) + 8 * (reg >> 2) + 4 * khw;
            if (row < nrows)
                H[(size_t)row * OUTC + c0 + wc * (BN / 2) + cg * 32 + r31] = acc[cg][reg];
        }
    }
}

// ---------------- per-node attention logits ----------------
__global__ void alpha_kernel(const float* __restrict__ h, const float* __restrict__ a_s,
                             const float* __restrict__ a_d, float* __restrict__ alpha_s,
                             float* __restrict__ alpha_d, int n_nodes, int heads) {
    const int gw = (blockIdx.x * blockDim.x + threadIdx.x) >> 6;
    const int lane = threadIdx.x & 63;
    const int total = n_nodes * heads;
    if (gw >= total) return;
    const int n = gw / heads;
    const int hd = gw - n * heads;
    const float v = h[(size_t)n * heads * 64 + hd * 64 + lane];
    float vs = v * a_s[hd * 64 + lane];
    float vd = v * a_d[hd * 64 + lane];
#pragma unroll
    for (int o = 32; o; o >>= 1) {
        vs += __shfl_xor(vs, o);
        vd += __shfl_xor(vd, o);
    }
    if (lane == 0) {
        alpha_s[gw] = vs;
        alpha_d[gw] = vd;
    }
}

__device__ __forceinline__ float leaky(float e) {
    return (e > 0.f) ? e : NEG_SLOPE * e;
}

// ---------------- softmax: e -> unnormalized ex (in w) + per-node recip ----------------
// One wave per node. Pass 1: random-gather alpha_s once, store raw e (seq), track max.
// Pass 2: seq re-read e, write ex=exp(e-m), accumulate sum -> rcp.
__global__ __launch_bounds__(256) void maxsum4_kernel(const float* __restrict__ alpha_s,
                                                      const float* __restrict__ alpha_d,
                                                      const int* __restrict__ offs,
                                                      const int* __restrict__ csr,
                                                      float* __restrict__ w,
                                                      float* __restrict__ rcp, int n_nodes) {
    const int n = (blockIdx.x * blockDim.x + threadIdx.x) >> 6;
    const int lane = threadIdx.x & 63;
    if (n >= n_nodes) return;
    const int start = offs[n];
    const int end = offs[n + 1];
    const float4 ad = *reinterpret_cast<const float4*>(&alpha_d[(size_t)n * 4]);

    float4 m = make_float4(-INFINITY, -INFINITY, -INFINITY, -INFINITY);
    for (int i = start + lane; i < end; i += 64) {
        const int s = csr[i];
        const float4 a = *reinterpret_cast<const float4*>(&alpha_s[(size_t)s * 4]);
        float4 e;
        e.x = leaky(a.x + ad.x);
        e.y = leaky(a.y + ad.y);
        e.z = leaky(a.z + ad.z);
        e.w = leaky(a.w + ad.w);
        *reinterpret_cast<float4*>(&w[(size_t)i * 4]) = e;
        m.x = fmaxf(m.x, e.x);
        m.y = fmaxf(m.y, e.y);
        m.z = fmaxf(m.z, e.z);
        m.w = fmaxf(m.w, e.w);
    }
#pragma unroll
    for (int o = 32; o; o >>= 1) {
        m.x = fmaxf(m.x, __shfl_xor(m.x, o));
        m.y = fmaxf(m.y, __shfl_xor(m.y, o));
        m.z = fmaxf(m.z, __shfl_xor(m.z, o));
        m.w = fmaxf(m.w, __shfl_xor(m.w, o));
    }
    float4 sum = make_float4(0.f, 0.f, 0.f, 0.f);
    for (int i = start + lane; i < end; i += 64) {
        float4 e = *reinterpret_cast<float4*>(&w[(size_t)i * 4]);
        e.x = __expf(e.x - m.x);
        e.y = __expf(e.y - m.y);
        e.z = __expf(e.z - m.z);
        e.w = __expf(e.w - m.w);
        *reinterpret_cast<float4*>(&w[(size_t)i * 4]) = e;
        sum.x += e.x;
        sum.y += e.y;
        sum.z += e.z;
        sum.w += e.w;
    }
#pragma unroll
    for (int o = 32; o; o >>= 1) {
        sum.x += __shfl_xor(sum.x, o);
        sum.y += __shfl_xor(sum.y, o);
        sum.z += __shfl_xor(sum.z, o);
        sum.w += __shfl_xor(sum.w, o);
    }
    if (lane == 0) {
        float4 r;
        r.x = 1.f / (sum.x + 1e-16f);
        r.y = 1.f / (sum.y + 1e-16f);
        r.z = 1.f / (sum.z + 1e-16f);
        r.w = 1.f / (sum.w + 1e-16f);
        *reinterpret_cast<float4*>(&rcp[(size_t)n * 4]) = r;
    }
}

__global__ __launch_bounds__(256) void maxsum1_kernel(const float* __restrict__ alpha_s,
                                                      const float* __restrict__ alpha_d,
                                                      const int* __restrict__ offs,
                                                      const int* __restrict__ csr,
                                                      float* __restrict__ w,
                                                      float* __restrict__ rcp, int n_nodes) {
    const int n = (blockIdx.x * blockDim.x + threadIdx.x) >> 6;
    const int lane = threadIdx.x & 63;
    if (n >= n_nodes) return;
    const int start = offs[n];
    const int end = offs[n + 1];
    const float ad = alpha_d[n];

    float m = -INFINITY;
    for (int i = start + lane; i < end; i += 64) {
        const float e = leaky(alpha_s[csr[i]] + ad);
        w[i] = e;
        m = fmaxf(m, e);
    }
#pragma unroll
    for (int o = 32; o; o >>= 1) m = fmaxf(m, __shfl_xor(m, o));
    float sum = 0.f;
    for (int i = start + lane; i < end; i += 64) {
        const float e = __expf(w[i] - m);
        w[i] = e;
        sum += e;
    }
#pragma unroll
    for (int o = 32; o; o >>= 1) sum += __shfl_xor(sum, o);
    if (lane == 0) rcp[n] = 1.f / (sum + 1e-16f);
}

// ---------------- aggregation: one wave per node, all 4 heads ----------------
// Per edge: 1 csr + 1 float4 w + 4 independent 256B gathers (1KB contiguous).
// 2-edge unroll -> 8 gathers in flight. Final scale by per-node recip.
template <bool RELU>
__global__ __launch_bounds__(256) void agg4_kernel(const float* __restrict__ h,
                                                   const float* __restrict__ w,
                                                   const float* __restrict__ rcp,
                                                   const int* __restrict__ offs,
                                                   const int* __restrict__ csr,
                                                   const float* __restrict__ bias,
                                                   float* __restrict__ out, int n_nodes) {
    const int n = (blockIdx.x * blockDim.x + threadIdx.x) >> 6;
    const int c = threadIdx.x & 63;
    if (n >= n_nodes) return;
    const int start = offs[n];
    const int end = offs[n + 1];

    float acc0 = 0.f, acc1 = 0.f, acc2 = 0.f, acc3 = 0.f;
    int i = start;
    for (; i + 1 < end; i += 2) {
        const int s0 = csr[i];
        const int s1 = csr[i + 1];
        const float4 w0 = *reinterpret_cast<const float4*>(&w[(size_t)i * 4]);
        const float4 w1 = *reinterpret_cast<const float4*>(&w[(size_t)(i + 1) * 4]);
        const float* r0 = &h[(size_t)s0 * 256 + c];
        const float* r1 = &h[(size_t)s1 * 256 + c];
        const float a0 = r0[0], a1 = r0[64], a2 = r0[128], a3 = r0[192];
        const float b0 = r1[0], b1 = r1[64], b2 = r1[128], b3 = r1[192];
        acc0 = fmaf(w0.x, a0, acc0);
        acc1 = fmaf(w0.y, a1, acc1);
        acc2 = fmaf(w0.z, a2, acc2);
        acc3 = fmaf(w0.w, a3, acc3);
        acc0 = fmaf(w1.x, b0, acc0);
        acc1 = fmaf(w1.y, b1, acc1);
        acc2 = fmaf(w1.z, b2, acc2);
        acc3 = fmaf(w1.w, b3, acc3);
    }
    if (i < end) {
        const int s0 = csr[i];
        const float4 w0 = *reinterpret_cast<const float4*>(&w[(size_t)i * 4]);
        const float* r0 = &h[(size_t)s0 * 256 + c];
        acc0 = fmaf(w0.x, r0[0], acc0);
        acc1 = fmaf(w0.y, r0[64], acc1);
        acc2 = fmaf(w0.z, r0[128], acc2);
        acc3 = fmaf(w0.w, r0[192], acc3);
    }
    const float4 r = *reinterpret_cast<const float4*>(&rcp[(size_t)n * 4]);
    float o0 = fmaf(acc0, r.x, 0.f) + bias[c];
    float o1 = fmaf(acc1, r.y, 0.f) + bias[64 + c];
    float o2 = fmaf(acc2, r.z, 0.f) + bias[128 + c];
    float o3 = fmaf(acc3, r.w, 0.f) + bias[192 + c];
    if (RELU) {
        o0 = fmaxf(o0, 0.f);
        o1 = fmaxf(o1, 0.f);
        o2 = fmaxf(o2, 0.f);
        o3 = fmaxf(o3, 0.f);
    }
    out[(size_t)n * 256 + c] = o0;
    out[(size_t)n * 256 + 64 + c] = o1;
    out[(size_t)n * 256 + 128 + c] = o2;
    out[(size_t)n * 256 + 192 + c] = o3;
}

template <bool RELU>
__global__ __launch_bounds__(256) void agg1_kernel(const float* __restrict__ h,
                                                   const float* __restrict__ w,
                                                   const float* __restrict__ rcp,
                                                   const int* __restrict__ offs,
                                                   const int* __restrict__ csr,
                                                   const float* __restrict__ bias,
                                                   float* __restrict__ out, int n_nodes) {
    const int n = (blockIdx.x * blockDim.x + threadIdx.x) >> 6;
    const int c = threadIdx.x & 63;
    if (n >= n_nodes) return;
    const int start = offs[n];
    const int end = offs[n + 1];

    float acc0 = 0.f, acc1 = 0.f, acc2 = 0.f, acc3 = 0.f;
    int i = start;
    for (; i + 3 < end; i += 4) {
        const int s0 = csr[i], s1 = csr[i + 1], s2 = csr[i + 2], s3 = csr[i + 3];
        const float w0 = w[i], w1 = w[i + 1], w2 = w[i + 2], w3 = w[i + 3];
        acc0 = fmaf(w0, h[(size_t)s0 * 64 + c], acc0);
        acc1 = fmaf(w1, h[(size_t)s1 * 64 + c], acc1);
        acc2 = fmaf(w2, h[(size_t)s2 * 64 + c], acc2);
        acc3 = fmaf(w3, h[(size_t)s3 * 64 + c], acc3);
    }
    for (; i < end; ++i) {
        acc0 = fmaf(w[i], h[(size_t)csr[i] * 64 + c], acc0);
    }
    float o = (acc0 + acc1 + acc2 + acc3) * rcp[n] + bias[c];
    if (RELU) o = fmaxf(o, 0.f);
    out[(size_t)n * 64 + c] = o;
}

// ---------------- launch ----------------
extern "C" void kernel_launch(void* const* d_in, const int* in_sizes, int n_in,
                              void* d_out, int out_size, void* d_ws, size_t ws_size,
                              hipStream_t stream) {
    const float* x   = (const float*)d_in[0];
    const int*   ei  = (const int*)d_in[1];
    const float* W1  = (const float*)d_in[2];
    const float* a1s = (const float*)d_in[3];
    const float* a1d = (const float*)d_in[4];
    const float* b1  = (const float*)d_in[5];
    const float* W2  = (const float*)d_in[6];
    const float* a2s = (const float*)d_in[7];
    const float* a2d = (const float*)d_in[8];
    const float* b2  = (const float*)d_in[9];
    const float* W3  = (const float*)d_in[10];
    const float* a3s = (const float*)d_in[11];
    const float* a3d = (const float*)d_in[12];
    const float* b3  = (const float*)d_in[13];
    float* out = (float*)d_out;

    const int N = in_sizes[0] / HID;
    const int E = in_sizes[1] / 2;
    const int* src = ei;
    const int* dst = ei + E;

    char* p = (char*)d_ws;
    auto alloc = [&](size_t bytes) {
        char* q = p;
        p += (bytes + 255) & ~(size_t)255;
        return q;
    };
    float* bufA = (float*)alloc((size_t)N * 256 * 4);
    float* bufB = (float*)alloc((size_t)N * 256 * 4);
    float* alpS = (float*)alloc((size_t)N * NHEADS * 4);
    float* alpD = (float*)alloc((size_t)N * NHEADS * 4);
    float* wbuf = (float*)alloc((size_t)E * NHEADS * 4);
    float* rcp  = (float*)alloc((size_t)N * NHEADS * 4);
    int* counts = (int*)alloc((size_t)N * 4);
    int* offs   = (int*)alloc((size_t)(N + 1) * 4);
    int* wp     = (int*)alloc((size_t)N * 4);
    int* csr    = (int*)alloc((size_t)E * 4);
    unsigned short* wt1h = (unsigned short*)alloc((size_t)64 * 256 * 2);
    unsigned short* wt1l = (unsigned short*)alloc((size_t)64 * 256 * 2);
    unsigned short* wt2h = (unsigned short*)alloc((size_t)256 * 256 * 2);
    unsigned short* wt2l = (unsigned short*)alloc((size_t)256 * 256 * 2);
    unsigned short* wt3h = (unsigned short*)alloc((size_t)256 * 64 * 2);
    unsigned short* wt3l = (unsigned short*)alloc((size_t)256 * 64 * 2);

    wsplit_kernel<<<(64 * 256 + 255) / 256, 256, 0, stream>>>(W1, wt1h, wt1l, 64, 256);
    wsplit_kernel<<<(256 * 256 + 255) / 256, 256, 0, stream>>>(W2, wt2h, wt2l, 256, 256);
    wsplit_kernel<<<(256 * 64 + 255) / 256, 256, 0, stream>>>(W3, wt3h, wt3l, 256, 64);

    hipMemsetAsync(counts, 0, (size_t)N * 4, stream);
    const int eb = (E + 255) / 256;
    histo_kernel<<<eb, 256, 0, stream>>>(dst, counts, E);
    scan_kernel<<<1, 256, 0, stream>>>(counts, offs, wp, N);
    scatter_kernel<<<eb, 256, 0, stream>>>(src, dst, wp, csr, E);

    const int gb64 = (N + 63) / 64;
    const int nwb = (N * 64 + 255) / 256;  // wave-per-node launches

    // layer 1: x[N,64] @ W1[64,256]
    gemm_mfma_kernel<64, 256, 128><<<dim3(gb64, 2), 256, 0, stream>>>(x, wt1h, wt1l, bufA, N);
    alpha_kernel<<<(N * NHEADS * 64 + 255) / 256, 256, 0, stream>>>(bufA, a1s, a1d, alpS, alpD, N, NHEADS);
    maxsum4_kernel<<<nwb, 256, 0, stream>>>(alpS, alpD, offs, csr, wbuf, rcp, N);
    agg4_kernel<true><<<nwb, 256, 0, stream>>>(bufA, wbuf, rcp, offs, csr, b1, bufB, N);

    // layer 2: bufB[N,256] @ W2[256,256]
    gemm_mfma_kernel<256, 256, 128><<<dim3(gb64, 2), 256, 0, stream>>>(bufB, W2 ? wt2h : wt2h, wt2l, bufA, N);
    alpha_kernel<<<(N * NHEADS * 64 + 255) / 256, 256, 0, stream>>>(bufA, a2s, a2d, alpS, alpD, N, NHEADS);
    maxsum4_kernel<<<nwb, 256, 0, stream>>>(alpS, alpD, offs, csr, wbuf, rcp, N);
    agg4_kernel<true><<<nwb, 256, 0, stream>>>(bufA, wbuf, rcp, offs, csr, b2, bufB, N);

    // layer 3: bufB[N,256] @ W3[256,64]
    gemm_mfma_kernel<256, 64, 64><<<dim3(gb64, 1), 256, 0, stream>>>(bufB, wt3h, wt3l, bufA, N);
    alpha_kernel<<<(N * 1 * 64 + 255) / 256, 256, 0, stream>>>(bufA, a3s, a3d, alpS, alpD, N, 1);
    maxsum1_kernel<<<nwb, 256, 0, stream>>>(alpS, alpD, offs, csr, wbuf, rcp, N);
    agg1_kernel<false><<<nwb, 256, 0, stream>>>(bufA, wbuf, rcp, offs, csr, b3, out, N);
}

// Round 7
// 276.600 us; speedup vs baseline: 1.5539x; 1.1362x over previous
//
#include <hip/hip_runtime.h>
#include <hip/hip_bf16.h>
#include <cstdint>

#define HID 64
#define NHEADS 4
#define NEG_SLOPE 0.2f

typedef __attribute__((ext_vector_type(8))) short short8;
typedef __attribute__((ext_vector_type(16))) float f32x16;

__device__ __forceinline__ unsigned short f2bf(float f) {
    unsigned int u = __float_as_uint(f);
    unsigned int r = (u + 0x7FFFu + ((u >> 16) & 1u)) >> 16;
    return (unsigned short)r;
}
__device__ __forceinline__ float bf2f(unsigned short h) {
    return __uint_as_float(((unsigned int)h) << 16);
}

// ---------------- CSR build ----------------
__global__ void histo_kernel(const int* __restrict__ dst, int* __restrict__ counts, int E) {
    int i = blockIdx.x * blockDim.x + threadIdx.x;
    if (i < E) atomicAdd(&counts[dst[i]], 1);
}

// Phase A: block b reduces counts[b*256 .. +255] -> bsum[b]
__global__ __launch_bounds__(256) void scanA_kernel(const int* __restrict__ counts,
                                                    int* __restrict__ bsum, int n) {
    const int i = blockIdx.x * 256 + threadIdx.x;
    int v = (i < n) ? counts[i] : 0;
#pragma unroll
    for (int o = 32; o; o >>= 1) v += __shfl_xor(v, o);
    __shared__ int ws[4];
    if ((threadIdx.x & 63) == 0) ws[threadIdx.x >> 6] = v;
    __syncthreads();
    if (threadIdx.x == 0) bsum[blockIdx.x] = ws[0] + ws[1] + ws[2] + ws[3];
}

// Phase B: one block exclusive-scans bsum[nb] in place (nb <= 256)
__global__ __launch_bounds__(256) void scanB_kernel(int* __restrict__ bsum, int nb) {
    __shared__ int sh[256];
    const int t = threadIdx.x;
    const int v = (t < nb) ? bsum[t] : 0;
    sh[t] = v;
    __syncthreads();
    for (int o = 1; o < 256; o <<= 1) {
        int u = (t >= o) ? sh[t - o] : 0;
        __syncthreads();
        sh[t] += u;
        __syncthreads();
    }
    if (t < nb) bsum[t] = sh[t] - v;
}

// Phase C: intra-block exclusive scan + base, write offs & wp (+ offs[n])
__global__ __launch_bounds__(256) void scanC_kernel(const int* __restrict__ counts,
                                                    const int* __restrict__ bsum,
                                                    int* __restrict__ offs,
                                                    int* __restrict__ wp, int n) {
    __shared__ int sh[256];
    const int t = threadIdx.x;
    const int i = blockIdx.x * 256 + t;
    const int v = (i < n) ? counts[i] : 0;
    sh[t] = v;
    __syncthreads();
    for (int o = 1; o < 256; o <<= 1) {
        int u = (t >= o) ? sh[t - o] : 0;
        __syncthreads();
        sh[t] += u;
        __syncthreads();
    }
    const int base = bsum[blockIdx.x];
    if (i < n) {
        const int off = base + sh[t] - v;
        offs[i] = off;
        wp[i] = off;
        if (i == n - 1) offs[n] = base + sh[t];
    }
}

__global__ void scatter_kernel(const int* __restrict__ src, const int* __restrict__ dst,
                               int* __restrict__ wp, int* __restrict__ csr, int E) {
    int i = blockIdx.x * blockDim.x + threadIdx.x;
    if (i < E) {
        int d = dst[i];
        int p = atomicAdd(&wp[d], 1);
        csr[p] = src[i];
    }
}

// ---------------- W pre-split: WT_hi/WT_lo[c][k] bf16 from W[k][c] fp32 ----------------
__global__ void wsplit_kernel(const float* __restrict__ W, unsigned short* __restrict__ WTh,
                              unsigned short* __restrict__ WTl, int K, int OUTC) {
    int i = blockIdx.x * blockDim.x + threadIdx.x;
    if (i >= K * OUTC) return;
    int c = i / K;
    int k = i - c * K;
    float v = W[(size_t)k * OUTC + c];
    unsigned short h = f2bf(v);
    WTh[i] = h;
    WTl[i] = f2bf(v - bf2f(h));
}

// ---------------- GEMM via MFMA split-bf16 ----------------
template <int K, int OUTC, int BN>
__global__ __launch_bounds__(256) void gemm_mfma_kernel(const float* __restrict__ X,
                                                        const unsigned short* __restrict__ WTh,
                                                        const unsigned short* __restrict__ WTl,
                                                        float* __restrict__ H, int nrows) {
    constexpr int CGS = BN / 64;
    constexpr int NB = BN / 64;
    constexpr int TPC = 4 / NB;
    __shared__ short Ah[64 * 32];
    __shared__ short Al[64 * 32];
    __shared__ short Bh[BN * 32];
    __shared__ short Bl[BN * 32];

    const int tid = threadIdx.x;
    const int lane = tid & 63;
    const int wid = tid >> 6;
    const int wr = wid >> 1;
    const int wc = wid & 1;
    const int r31 = lane & 31;
    const int khw = lane >> 5;
    const int row0 = blockIdx.x * 64;
    const int c0 = blockIdx.y * BN;

    const int ar = tid >> 2;
    const int akq = (tid & 3) * 8;
    const int arow = row0 + ar;
    const bool aok = arow < nrows;

    const int bcol = tid / TPC;
    const int bkb = (tid % TPC) * NB;

    f32x16 acc[CGS];
#pragma unroll
    for (int cg = 0; cg < CGS; ++cg)
#pragma unroll
        for (int r = 0; r < 16; ++r) acc[cg][r] = 0.f;

    for (int k0 = 0; k0 < K; k0 += 32) {
        __syncthreads();
        {
            float4 v0 = make_float4(0.f, 0.f, 0.f, 0.f), v1 = v0;
            if (aok) {
                v0 = *reinterpret_cast<const float4*>(&X[(size_t)arow * K + k0 + akq]);
                v1 = *reinterpret_cast<const float4*>(&X[(size_t)arow * K + k0 + akq + 4]);
            }
            float vs[8] = {v0.x, v0.y, v0.z, v0.w, v1.x, v1.y, v1.z, v1.w};
            short8 hi, lo;
#pragma unroll
            for (int j = 0; j < 8; ++j) {
                unsigned short h = f2bf(vs[j]);
                hi[j] = (short)h;
                lo[j] = (short)f2bf(vs[j] - bf2f(h));
            }
            const int blk = (akq >> 3) ^ (ar & 3);
            const int off = ar * 32 + (blk << 3);
            *reinterpret_cast<short8*>(&Ah[off]) = hi;
            *reinterpret_cast<short8*>(&Al[off]) = lo;
        }
        {
            const unsigned short* srcH = &WTh[(size_t)(c0 + bcol) * K + k0 + bkb * 8];
            const unsigned short* srcL = &WTl[(size_t)(c0 + bcol) * K + k0 + bkb * 8];
#pragma unroll
            for (int b = 0; b < NB; ++b) {
                short8 h = *reinterpret_cast<const short8*>(&srcH[b * 8]);
                short8 l = *reinterpret_cast<const short8*>(&srcL[b * 8]);
                const int blk = (bkb + b) ^ (bcol & 3);
                const int off = bcol * 32 + (blk << 3);
                *reinterpret_cast<short8*>(&Bh[off]) = h;
                *reinterpret_cast<short8*>(&Bl[off]) = l;
            }
        }
        __syncthreads();
#pragma unroll
        for (int ks = 0; ks < 32; ks += 16) {
            const int kb = (ks >> 3) + khw;
            const int aoff = (wr * 32 + r31) * 32 + ((kb ^ (r31 & 3)) << 3);
            short8 ah = *reinterpret_cast<const short8*>(&Ah[aoff]);
            short8 al = *reinterpret_cast<const short8*>(&Al[aoff]);
#pragma unroll
            for (int cg = 0; cg < CGS; ++cg) {
                const int coll = wc * (BN / 2) + cg * 32 + r31;
                const int boff = coll * 32 + ((kb ^ (r31 & 3)) << 3);
                short8 bh = *reinterpret_cast<const short8*>(&Bh[boff]);
                short8 bl = *reinterpret_cast<const short8*>(&Bl[boff]);
                acc[cg] = __builtin_amdgcn_mfma_f32_32x32x16_bf16(ah, bh, acc[cg], 0, 0, 0);
                acc[cg] = __builtin_amdgcn_mfma_f32_32x32x16_bf16(ah, bl, acc[cg], 0, 0, 0);
                acc[cg] = __builtin_amdgcn_mfma_f32_32x32x16_bf16(al, bh, acc[cg], 0, 0, 0);
            }
        }
    }

#pragma unroll
    for (int cg = 0; cg < CGS; ++cg) {
#pragma unroll
        for (int reg = 0; reg < 16; ++reg) {
            const int row = row0 + wr * 32 + (reg & 3) + 8 * (reg >> 2) + 4 * khw;
            if (row < nrows)
                H[(size_t)row * OUTC + c0 + wc * (BN / 2) + cg * 32 + r31] = acc[cg][reg];
        }
    }
}

// ---------------- per-node attention logits ----------------
__global__ void alpha_kernel(const float* __restrict__ h, const float* __restrict__ a_s,
                             const float* __restrict__ a_d, float* __restrict__ alpha_s,
                             float* __restrict__ alpha_d, int n_nodes, int heads) {
    const int gw = (blockIdx.x * blockDim.x + threadIdx.x) >> 6;
    const int lane = threadIdx.x & 63;
    const int total = n_nodes * heads;
    if (gw >= total) return;
    const int n = gw / heads;
    const int hd = gw - n * heads;
    const float v = h[(size_t)n * heads * 64 + hd * 64 + lane];
    float vs = v * a_s[hd * 64 + lane];
    float vd = v * a_d[hd * 64 + lane];
#pragma unroll
    for (int o = 32; o; o >>= 1) {
        vs += __shfl_xor(vs, o);
        vd += __shfl_xor(vd, o);
    }
    if (lane == 0) {
        alpha_s[gw] = vs;
        alpha_d[gw] = vd;
    }
}

__device__ __forceinline__ float leaky(float e) {
    return (e > 0.f) ? e : NEG_SLOPE * e;
}

// ---------------- softmax: e -> unnormalized ex (in w) + per-node recip ----------------
__global__ __launch_bounds__(256) void maxsum4_kernel(const float* __restrict__ alpha_s,
                                                      const float* __restrict__ alpha_d,
                                                      const int* __restrict__ offs,
                                                      const int* __restrict__ csr,
                                                      float* __restrict__ w,
                                                      float* __restrict__ rcp, int n_nodes) {
    const int n = (blockIdx.x * blockDim.x + threadIdx.x) >> 6;
    const int lane = threadIdx.x & 63;
    if (n >= n_nodes) return;
    const int start = offs[n];
    const int end = offs[n + 1];
    const float4 ad = *reinterpret_cast<const float4*>(&alpha_d[(size_t)n * 4]);

    float4 m = make_float4(-INFINITY, -INFINITY, -INFINITY, -INFINITY);
    for (int i = start + lane; i < end; i += 64) {
        const int s = csr[i];
        const float4 a = *reinterpret_cast<const float4*>(&alpha_s[(size_t)s * 4]);
        float4 e;
        e.x = leaky(a.x + ad.x);
        e.y = leaky(a.y + ad.y);
        e.z = leaky(a.z + ad.z);
        e.w = leaky(a.w + ad.w);
        *reinterpret_cast<float4*>(&w[(size_t)i * 4]) = e;
        m.x = fmaxf(m.x, e.x);
        m.y = fmaxf(m.y, e.y);
        m.z = fmaxf(m.z, e.z);
        m.w = fmaxf(m.w, e.w);
    }
#pragma unroll
    for (int o = 32; o; o >>= 1) {
        m.x = fmaxf(m.x, __shfl_xor(m.x, o));
        m.y = fmaxf(m.y, __shfl_xor(m.y, o));
        m.z = fmaxf(m.z, __shfl_xor(m.z, o));
        m.w = fmaxf(m.w, __shfl_xor(m.w, o));
    }
    float4 sum = make_float4(0.f, 0.f, 0.f, 0.f);
    for (int i = start + lane; i < end; i += 64) {
        float4 e = *reinterpret_cast<float4*>(&w[(size_t)i * 4]);
        e.x = __expf(e.x - m.x);
        e.y = __expf(e.y - m.y);
        e.z = __expf(e.z - m.z);
        e.w = __expf(e.w - m.w);
        *reinterpret_cast<float4*>(&w[(size_t)i * 4]) = e;
        sum.x += e.x;
        sum.y += e.y;
        sum.z += e.z;
        sum.w += e.w;
    }
#pragma unroll
    for (int o = 32; o; o >>= 1) {
        sum.x += __shfl_xor(sum.x, o);
        sum.y += __shfl_xor(sum.y, o);
        sum.z += __shfl_xor(sum.z, o);
        sum.w += __shfl_xor(sum.w, o);
    }
    if (lane == 0) {
        float4 r;
        r.x = 1.f / (sum.x + 1e-16f);
        r.y = 1.f / (sum.y + 1e-16f);
        r.z = 1.f / (sum.z + 1e-16f);
        r.w = 1.f / (sum.w + 1e-16f);
        *reinterpret_cast<float4*>(&rcp[(size_t)n * 4]) = r;
    }
}

__global__ __launch_bounds__(256) void maxsum1_kernel(const float* __restrict__ alpha_s,
                                                      const float* __restrict__ alpha_d,
                                                      const int* __restrict__ offs,
                                                      const int* __restrict__ csr,
                                                      float* __restrict__ w,
                                                      float* __restrict__ rcp, int n_nodes) {
    const int n = (blockIdx.x * blockDim.x + threadIdx.x) >> 6;
    const int lane = threadIdx.x & 63;
    if (n >= n_nodes) return;
    const int start = offs[n];
    const int end = offs[n + 1];
    const float ad = alpha_d[n];

    float m = -INFINITY;
    for (int i = start + lane; i < end; i += 64) {
        const float e = leaky(alpha_s[csr[i]] + ad);
        w[i] = e;
        m = fmaxf(m, e);
    }
#pragma unroll
    for (int o = 32; o; o >>= 1) m = fmaxf(m, __shfl_xor(m, o));
    float sum = 0.f;
    for (int i = start + lane; i < end; i += 64) {
        const float e = __expf(w[i] - m);
        w[i] = e;
        sum += e;
    }
#pragma unroll
    for (int o = 32; o; o >>= 1) sum += __shfl_xor(sum, o);
    if (lane == 0) rcp[n] = 1.f / (sum + 1e-16f);
}

// ---------------- aggregation ----------------
template <bool RELU>
__global__ __launch_bounds__(256) void agg4_kernel(const float* __restrict__ h,
                                                   const float* __restrict__ w,
                                                   const float* __restrict__ rcp,
                                                   const int* __restrict__ offs,
                                                   const int* __restrict__ csr,
                                                   const float* __restrict__ bias,
                                                   float* __restrict__ out, int n_nodes) {
    const int n = (blockIdx.x * blockDim.x + threadIdx.x) >> 6;
    const int c = threadIdx.x & 63;
    if (n >= n_nodes) return;
    const int start = offs[n];
    const int end = offs[n + 1];

    float acc0 = 0.f, acc1 = 0.f, acc2 = 0.f, acc3 = 0.f;
    int i = start;
    for (; i + 1 < end; i += 2) {
        const int s0 = csr[i];
        const int s1 = csr[i + 1];
        const float4 w0 = *reinterpret_cast<const float4*>(&w[(size_t)i * 4]);
        const float4 w1 = *reinterpret_cast<const float4*>(&w[(size_t)(i + 1) * 4]);
        const float* r0 = &h[(size_t)s0 * 256 + c];
        const float* r1 = &h[(size_t)s1 * 256 + c];
        const float a0 = r0[0], a1 = r0[64], a2 = r0[128], a3 = r0[192];
        const float b0 = r1[0], b1 = r1[64], b2 = r1[128], b3 = r1[192];
        acc0 = fmaf(w0.x, a0, acc0);
        acc1 = fmaf(w0.y, a1, acc1);
        acc2 = fmaf(w0.z, a2, acc2);
        acc3 = fmaf(w0.w, a3, acc3);
        acc0 = fmaf(w1.x, b0, acc0);
        acc1 = fmaf(w1.y, b1, acc1);
        acc2 = fmaf(w1.z, b2, acc2);
        acc3 = fmaf(w1.w, b3, acc3);
    }
    if (i < end) {
        const int s0 = csr[i];
        const float4 w0 = *reinterpret_cast<const float4*>(&w[(size_t)i * 4]);
        const float* r0 = &h[(size_t)s0 * 256 + c];
        acc0 = fmaf(w0.x, r0[0], acc0);
        acc1 = fmaf(w0.y, r0[64], acc1);
        acc2 = fmaf(w0.z, r0[128], acc2);
        acc3 = fmaf(w0.w, r0[192], acc3);
    }
    const float4 r = *reinterpret_cast<const float4*>(&rcp[(size_t)n * 4]);
    float o0 = acc0 * r.x + bias[c];
    float o1 = acc1 * r.y + bias[64 + c];
    float o2 = acc2 * r.z + bias[128 + c];
    float o3 = acc3 * r.w + bias[192 + c];
    if (RELU) {
        o0 = fmaxf(o0, 0.f);
        o1 = fmaxf(o1, 0.f);
        o2 = fmaxf(o2, 0.f);
        o3 = fmaxf(o3, 0.f);
    }
    out[(size_t)n * 256 + c] = o0;
    out[(size_t)n * 256 + 64 + c] = o1;
    out[(size_t)n * 256 + 128 + c] = o2;
    out[(size_t)n * 256 + 192 + c] = o3;
}

template <bool RELU>
__global__ __launch_bounds__(256) void agg1_kernel(const float* __restrict__ h,
                                                   const float* __restrict__ w,
                                                   const float* __restrict__ rcp,
                                                   const int* __restrict__ offs,
                                                   const int* __restrict__ csr,
                                                   const float* __restrict__ bias,
                                                   float* __restrict__ out, int n_nodes) {
    const int n = (blockIdx.x * blockDim.x + threadIdx.x) >> 6;
    const int c = threadIdx.x & 63;
    if (n >= n_nodes) return;
    const int start = offs[n];
    const int end = offs[n + 1];

    float acc0 = 0.f, acc1 = 0.f, acc2 = 0.f, acc3 = 0.f;
    int i = start;
    for (; i + 3 < end; i += 4) {
        const int s0 = csr[i], s1 = csr[i + 1], s2 = csr[i + 2], s3 = csr[i + 3];
        const float w0 = w[i], w1 = w[i + 1], w2 = w[i + 2], w3 = w[i + 3];
        acc0 = fmaf(w0, h[(size_t)s0 * 64 + c], acc0);
        acc1 = fmaf(w1, h[(size_t)s1 * 64 + c], acc1);
        acc2 = fmaf(w2, h[(size_t)s2 * 64 + c], acc2);
        acc3 = fmaf(w3, h[(size_t)s3 * 64 + c], acc3);
    }
    for (; i < end; ++i) {
        acc0 = fmaf(w[i], h[(size_t)csr[i] * 64 + c], acc0);
    }
    float o = (acc0 + acc1 + acc2 + acc3) * rcp[n] + bias[c];
    if (RELU) o = fmaxf(o, 0.f);
    out[(size_t)n * 64 + c] = o;
}

// ---------------- launch ----------------
extern "C" void kernel_launch(void* const* d_in, const int* in_sizes, int n_in,
                              void* d_out, int out_size, void* d_ws, size_t ws_size,
                              hipStream_t stream) {
    const float* x   = (const float*)d_in[0];
    const int*   ei  = (const int*)d_in[1];
    const float* W1  = (const float*)d_in[2];
    const float* a1s = (const float*)d_in[3];
    const float* a1d = (const float*)d_in[4];
    const float* b1  = (const float*)d_in[5];
    const float* W2  = (const float*)d_in[6];
    const float* a2s = (const float*)d_in[7];
    const float* a2d = (const float*)d_in[8];
    const float* b2  = (const float*)d_in[9];
    const float* W3  = (const float*)d_in[10];
    const float* a3s = (const float*)d_in[11];
    const float* a3d = (const float*)d_in[12];
    const float* b3  = (const float*)d_in[13];
    float* out = (float*)d_out;

    const int N = in_sizes[0] / HID;
    const int E = in_sizes[1] / 2;
    const int* src = ei;
    const int* dst = ei + E;

    char* p = (char*)d_ws;
    auto alloc = [&](size_t bytes) {
        char* q = p;
        p += (bytes + 255) & ~(size_t)255;
        return q;
    };
    float* bufA = (float*)alloc((size_t)N * 256 * 4);
    float* bufB = (float*)alloc((size_t)N * 256 * 4);
    float* alpS = (float*)alloc((size_t)N * NHEADS * 4);
    float* alpD = (float*)alloc((size_t)N * NHEADS * 4);
    float* wbuf = (float*)alloc((size_t)E * NHEADS * 4);
    float* rcp  = (float*)alloc((size_t)N * NHEADS * 4);
    int* counts = (int*)alloc((size_t)N * 4);
    int* offs   = (int*)alloc((size_t)(N + 1) * 4);
    int* wp     = (int*)alloc((size_t)N * 4);
    int* csr    = (int*)alloc((size_t)E * 4);
    int* bsum   = (int*)alloc((size_t)256 * 4);
    unsigned short* wt1h = (unsigned short*)alloc((size_t)64 * 256 * 2);
    unsigned short* wt1l = (unsigned short*)alloc((size_t)64 * 256 * 2);
    unsigned short* wt2h = (unsigned short*)alloc((size_t)256 * 256 * 2);
    unsigned short* wt2l = (unsigned short*)alloc((size_t)256 * 256 * 2);
    unsigned short* wt3h = (unsigned short*)alloc((size_t)256 * 64 * 2);
    unsigned short* wt3l = (unsigned short*)alloc((size_t)256 * 64 * 2);

    wsplit_kernel<<<(64 * 256 + 255) / 256, 256, 0, stream>>>(W1, wt1h, wt1l, 64, 256);
    wsplit_kernel<<<(256 * 256 + 255) / 256, 256, 0, stream>>>(W2, wt2h, wt2l, 256, 256);
    wsplit_kernel<<<(256 * 64 + 255) / 256, 256, 0, stream>>>(W3, wt3h, wt3l, 256, 64);

    hipMemsetAsync(counts, 0, (size_t)N * 4, stream);
    const int eb = (E + 255) / 256;
    const int nb = (N + 255) / 256;
    histo_kernel<<<eb, 256, 0, stream>>>(dst, counts, E);
    scanA_kernel<<<nb, 256, 0, stream>>>(counts, bsum, N);
    scanB_kernel<<<1, 256, 0, stream>>>(bsum, nb);
    scanC_kernel<<<nb, 256, 0, stream>>>(counts, bsum, offs, wp, N);
    scatter_kernel<<<eb, 256, 0, stream>>>(src, dst, wp, csr, E);

    const int gb64 = (N + 63) / 64;
    const int nwb = (N * 64 + 255) / 256;  // wave-per-node launches

    // layer 1: x[N,64] @ W1[64,256]
    gemm_mfma_kernel<64, 256, 128><<<dim3(gb64, 2), 256, 0, stream>>>(x, wt1h, wt1l, bufA, N);
    alpha_kernel<<<(N * NHEADS * 64 + 255) / 256, 256, 0, stream>>>(bufA, a1s, a1d, alpS, alpD, N, NHEADS);
    maxsum4_kernel<<<nwb, 256, 0, stream>>>(alpS, alpD, offs, csr, wbuf, rcp, N);
    agg4_kernel<true><<<nwb, 256, 0, stream>>>(bufA, wbuf, rcp, offs, csr, b1, bufB, N);

    // layer 2: bufB[N,256] @ W2[256,256]
    gemm_mfma_kernel<256, 256, 128><<<dim3(gb64, 2), 256, 0, stream>>>(bufB, wt2h, wt2l, bufA, N);
    alpha_kernel<<<(N * NHEADS * 64 + 255) / 256, 256, 0, stream>>>(bufA, a2s, a2d, alpS, alpD, N, NHEADS);
    maxsum4_kernel<<<nwb, 256, 0, stream>>>(alpS, alpD, offs, csr, wbuf, rcp, N);
    agg4_kernel<true><<<nwb, 256, 0, stream>>>(bufA, wbuf, rcp, offs, csr, b2, bufB, N);

    // layer 3: bufB[N,256] @ W3[256,64]
    gemm_mfma_kernel<256, 64, 64><<<dim3(gb64, 1), 256, 0, stream>>>(bufB, wt3h, wt3l, bufA, N);
    alpha_kernel<<<(N * 1 * 64 + 255) / 256, 256, 0, stream>>>(bufA, a3s, a3d, alpS, alpD, N, 1);
    maxsum1_kernel<<<nwb, 256, 0, stream>>>(alpS, alpD, offs, csr, wbuf, rcp, N);
    agg1_kernel<false><<<nwb, 256, 0, stream>>>(bufA, wbuf, rcp, offs, csr, b3, out, N);
}

// Round 8
// 238.995 us; speedup vs baseline: 1.7984x; 1.1573x over previous
//
#include <hip/hip_runtime.h>
#include <hip/hip_bf16.h>
#include <hip/hip_fp16.h>
#include <cstdint>

#define HID 64
#define NHEADS 4
#define NEG_SLOPE 0.2f

typedef __attribute__((ext_vector_type(8))) short short8;
typedef __attribute__((ext_vector_type(16))) float f32x16;

__device__ __forceinline__ unsigned short f2bf(float f) {
    unsigned int u = __float_as_uint(f);
    unsigned int r = (u + 0x7FFFu + ((u >> 16) & 1u)) >> 16;
    return (unsigned short)r;
}
__device__ __forceinline__ float bf2f(unsigned short h) {
    return __uint_as_float(((unsigned int)h) << 16);
}

// ---------------- CSR build ----------------
__global__ void histo_kernel(const int* __restrict__ dst, int* __restrict__ counts, int E) {
    int i = blockIdx.x * blockDim.x + threadIdx.x;
    if (i < E) atomicAdd(&counts[dst[i]], 1);
}

__global__ __launch_bounds__(256) void scanA_kernel(const int* __restrict__ counts,
                                                    int* __restrict__ bsum, int n) {
    const int i = blockIdx.x * 256 + threadIdx.x;
    int v = (i < n) ? counts[i] : 0;
#pragma unroll
    for (int o = 32; o; o >>= 1) v += __shfl_xor(v, o);
    __shared__ int ws[4];
    if ((threadIdx.x & 63) == 0) ws[threadIdx.x >> 6] = v;
    __syncthreads();
    if (threadIdx.x == 0) bsum[blockIdx.x] = ws[0] + ws[1] + ws[2] + ws[3];
}

__global__ __launch_bounds__(256) void scanB_kernel(int* __restrict__ bsum, int nb) {
    __shared__ int sh[256];
    const int t = threadIdx.x;
    const int v = (t < nb) ? bsum[t] : 0;
    sh[t] = v;
    __syncthreads();
    for (int o = 1; o < 256; o <<= 1) {
        int u = (t >= o) ? sh[t - o] : 0;
        __syncthreads();
        sh[t] += u;
        __syncthreads();
    }
    if (t < nb) bsum[t] = sh[t] - v;
}

__global__ __launch_bounds__(256) void scanC_kernel(const int* __restrict__ counts,
                                                    const int* __restrict__ bsum,
                                                    int* __restrict__ offs,
                                                    int* __restrict__ wp, int n) {
    __shared__ int sh[256];
    const int t = threadIdx.x;
    const int i = blockIdx.x * 256 + t;
    const int v = (i < n) ? counts[i] : 0;
    sh[t] = v;
    __syncthreads();
    for (int o = 1; o < 256; o <<= 1) {
        int u = (t >= o) ? sh[t - o] : 0;
        __syncthreads();
        sh[t] += u;
        __syncthreads();
    }
    const int base = bsum[blockIdx.x];
    if (i < n) {
        const int off = base + sh[t] - v;
        offs[i] = off;
        wp[i] = off;
        if (i == n - 1) offs[n] = base + sh[t];
    }
}

__global__ void scatter_kernel(const int* __restrict__ src, const int* __restrict__ dst,
                               int* __restrict__ wp, int* __restrict__ csr, int E) {
    int i = blockIdx.x * blockDim.x + threadIdx.x;
    if (i < E) {
        int d = dst[i];
        int p = atomicAdd(&wp[d], 1);
        csr[p] = src[i];
    }
}

// ---------------- W pre-split ----------------
__global__ void wsplit_kernel(const float* __restrict__ W, unsigned short* __restrict__ WTh,
                              unsigned short* __restrict__ WTl, int K, int OUTC) {
    int i = blockIdx.x * blockDim.x + threadIdx.x;
    if (i >= K * OUTC) return;
    int c = i / K;
    int k = i - c * K;
    float v = W[(size_t)k * OUTC + c];
    unsigned short h = f2bf(v);
    WTh[i] = h;
    WTl[i] = f2bf(v - bf2f(h));
}

// ---------------- GEMM via MFMA split-bf16, dual fp32+fp16 output ----------------
template <int K, int OUTC, int BN>
__global__ __launch_bounds__(256) void gemm_mfma_kernel(const float* __restrict__ X,
                                                        const unsigned short* __restrict__ WTh,
                                                        const unsigned short* __restrict__ WTl,
                                                        float* __restrict__ H,
                                                        _Float16* __restrict__ H16, int nrows) {
    constexpr int CGS = BN / 64;
    constexpr int NB = BN / 64;
    constexpr int TPC = 4 / NB;
    __shared__ short Ah[64 * 32];
    __shared__ short Al[64 * 32];
    __shared__ short Bh[BN * 32];
    __shared__ short Bl[BN * 32];

    const int tid = threadIdx.x;
    const int lane = tid & 63;
    const int wid = tid >> 6;
    const int wr = wid >> 1;
    const int wc = wid & 1;
    const int r31 = lane & 31;
    const int khw = lane >> 5;
    const int row0 = blockIdx.x * 64;
    const int c0 = blockIdx.y * BN;

    const int ar = tid >> 2;
    const int akq = (tid & 3) * 8;
    const int arow = row0 + ar;
    const bool aok = arow < nrows;

    const int bcol = tid / TPC;
    const int bkb = (tid % TPC) * NB;

    f32x16 acc[CGS];
#pragma unroll
    for (int cg = 0; cg < CGS; ++cg)
#pragma unroll
        for (int r = 0; r < 16; ++r) acc[cg][r] = 0.f;

    for (int k0 = 0; k0 < K; k0 += 32) {
        __syncthreads();
        {
            float4 v0 = make_float4(0.f, 0.f, 0.f, 0.f), v1 = v0;
            if (aok) {
                v0 = *reinterpret_cast<const float4*>(&X[(size_t)arow * K + k0 + akq]);
                v1 = *reinterpret_cast<const float4*>(&X[(size_t)arow * K + k0 + akq + 4]);
            }
            float vs[8] = {v0.x, v0.y, v0.z, v0.w, v1.x, v1.y, v1.z, v1.w};
            short8 hi, lo;
#pragma unroll
            for (int j = 0; j < 8; ++j) {
                unsigned short h = f2bf(vs[j]);
                hi[j] = (short)h;
                lo[j] = (short)f2bf(vs[j] - bf2f(h));
            }
            const int blk = (akq >> 3) ^ (ar & 3);
            const int off = ar * 32 + (blk << 3);
            *reinterpret_cast<short8*>(&Ah[off]) = hi;
            *reinterpret_cast<short8*>(&Al[off]) = lo;
        }
        {
            const unsigned short* srcH = &WTh[(size_t)(c0 + bcol) * K + k0 + bkb * 8];
            const unsigned short* srcL = &WTl[(size_t)(c0 + bcol) * K + k0 + bkb * 8];
#pragma unroll
            for (int b = 0; b < NB; ++b) {
                short8 h = *reinterpret_cast<const short8*>(&srcH[b * 8]);
                short8 l = *reinterpret_cast<const short8*>(&srcL[b * 8]);
                const int blk = (bkb + b) ^ (bcol & 3);
                const int off = bcol * 32 + (blk << 3);
                *reinterpret_cast<short8*>(&Bh[off]) = h;
                *reinterpret_cast<short8*>(&Bl[off]) = l;
            }
        }
        __syncthreads();
#pragma unroll
        for (int ks = 0; ks < 32; ks += 16) {
            const int kb = (ks >> 3) + khw;
            const int aoff = (wr * 32 + r31) * 32 + ((kb ^ (r31 & 3)) << 3);
            short8 ah = *reinterpret_cast<const short8*>(&Ah[aoff]);
            short8 al = *reinterpret_cast<const short8*>(&Al[aoff]);
#pragma unroll
            for (int cg = 0; cg < CGS; ++cg) {
                const int coll = wc * (BN / 2) + cg * 32 + r31;
                const int boff = coll * 32 + ((kb ^ (r31 & 3)) << 3);
                short8 bh = *reinterpret_cast<const short8*>(&Bh[boff]);
                short8 bl = *reinterpret_cast<const short8*>(&Bl[boff]);
                acc[cg] = __builtin_amdgcn_mfma_f32_32x32x16_bf16(ah, bh, acc[cg], 0, 0, 0);
                acc[cg] = __builtin_amdgcn_mfma_f32_32x32x16_bf16(ah, bl, acc[cg], 0, 0, 0);
                acc[cg] = __builtin_amdgcn_mfma_f32_32x32x16_bf16(al, bh, acc[cg], 0, 0, 0);
            }
        }
    }

#pragma unroll
    for (int cg = 0; cg < CGS; ++cg) {
#pragma unroll
        for (int reg = 0; reg < 16; ++reg) {
            const int row = row0 + wr * 32 + (reg & 3) + 8 * (reg >> 2) + 4 * khw;
            if (row < nrows) {
                const int col = c0 + wc * (BN / 2) + cg * 32 + r31;
                const float v = acc[cg][reg];
                H[(size_t)row * OUTC + col] = v;
                H16[(size_t)row * OUTC + col] = (_Float16)v;
            }
        }
    }
}

// ---------------- per-node attention logits ----------------
__global__ void alpha_kernel(const float* __restrict__ h, const float* __restrict__ a_s,
                             const float* __restrict__ a_d, float* __restrict__ alpha_s,
                             float* __restrict__ alpha_d, int n_nodes, int heads) {
    const int gw = (blockIdx.x * blockDim.x + threadIdx.x) >> 6;
    const int lane = threadIdx.x & 63;
    const int total = n_nodes * heads;
    if (gw >= total) return;
    const int n = gw / heads;
    const int hd = gw - n * heads;
    const float v = h[(size_t)n * heads * 64 + hd * 64 + lane];
    float vs = v * a_s[hd * 64 + lane];
    float vd = v * a_d[hd * 64 + lane];
#pragma unroll
    for (int o = 32; o; o >>= 1) {
        vs += __shfl_xor(vs, o);
        vd += __shfl_xor(vd, o);
    }
    if (lane == 0) {
        alpha_s[gw] = vs;
        alpha_d[gw] = vd;
    }
}

__device__ __forceinline__ float leaky(float e) {
    return (e > 0.f) ? e : NEG_SLOPE * e;
}

// ---------------- softmax: unnormalized ex (in w) + per-node recip ----------------
__global__ __launch_bounds__(256) void maxsum4_kernel(const float* __restrict__ alpha_s,
                                                      const float* __restrict__ alpha_d,
                                                      const int* __restrict__ offs,
                                                      const int* __restrict__ csr,
                                                      float* __restrict__ w,
                                                      float* __restrict__ rcp, int n_nodes) {
    const int n = (blockIdx.x * blockDim.x + threadIdx.x) >> 6;
    const int lane = threadIdx.x & 63;
    if (n >= n_nodes) return;
    const int start = offs[n];
    const int end = offs[n + 1];
    const float4 ad = *reinterpret_cast<const float4*>(&alpha_d[(size_t)n * 4]);

    float4 m = make_float4(-INFINITY, -INFINITY, -INFINITY, -INFINITY);
    for (int i = start + lane; i < end; i += 64) {
        const int s = csr[i];
        const float4 a = *reinterpret_cast<const float4*>(&alpha_s[(size_t)s * 4]);
        float4 e;
        e.x = leaky(a.x + ad.x);
        e.y = leaky(a.y + ad.y);
        e.z = leaky(a.z + ad.z);
        e.w = leaky(a.w + ad.w);
        *reinterpret_cast<float4*>(&w[(size_t)i * 4]) = e;
        m.x = fmaxf(m.x, e.x);
        m.y = fmaxf(m.y, e.y);
        m.z = fmaxf(m.z, e.z);
        m.w = fmaxf(m.w, e.w);
    }
#pragma unroll
    for (int o = 32; o; o >>= 1) {
        m.x = fmaxf(m.x, __shfl_xor(m.x, o));
        m.y = fmaxf(m.y, __shfl_xor(m.y, o));
        m.z = fmaxf(m.z, __shfl_xor(m.z, o));
        m.w = fmaxf(m.w, __shfl_xor(m.w, o));
    }
    float4 sum = make_float4(0.f, 0.f, 0.f, 0.f);
    for (int i = start + lane; i < end; i += 64) {
        float4 e = *reinterpret_cast<float4*>(&w[(size_t)i * 4]);
        e.x = __expf(e.x - m.x);
        e.y = __expf(e.y - m.y);
        e.z = __expf(e.z - m.z);
        e.w = __expf(e.w - m.w);
        *reinterpret_cast<float4*>(&w[(size_t)i * 4]) = e;
        sum.x += e.x;
        sum.y += e.y;
        sum.z += e.z;
        sum.w += e.w;
    }
#pragma unroll
    for (int o = 32; o; o >>= 1) {
        sum.x += __shfl_xor(sum.x, o);
        sum.y += __shfl_xor(sum.y, o);
        sum.z += __shfl_xor(sum.z, o);
        sum.w += __shfl_xor(sum.w, o);
    }
    if (lane == 0) {
        float4 r;
        r.x = 1.f / (sum.x + 1e-16f);
        r.y = 1.f / (sum.y + 1e-16f);
        r.z = 1.f / (sum.z + 1e-16f);
        r.w = 1.f / (sum.w + 1e-16f);
        *reinterpret_cast<float4*>(&rcp[(size_t)n * 4]) = r;
    }
}

__global__ __launch_bounds__(256) void maxsum1_kernel(const float* __restrict__ alpha_s,
                                                      const float* __restrict__ alpha_d,
                                                      const int* __restrict__ offs,
                                                      const int* __restrict__ csr,
                                                      float* __restrict__ w,
                                                      float* __restrict__ rcp, int n_nodes) {
    const int n = (blockIdx.x * blockDim.x + threadIdx.x) >> 6;
    const int lane = threadIdx.x & 63;
    if (n >= n_nodes) return;
    const int start = offs[n];
    const int end = offs[n + 1];
    const float ad = alpha_d[n];

    float m = -INFINITY;
    for (int i = start + lane; i < end; i += 64) {
        const float e = leaky(alpha_s[csr[i]] + ad);
        w[i] = e;
        m = fmaxf(m, e);
    }
#pragma unroll
    for (int o = 32; o; o >>= 1) m = fmaxf(m, __shfl_xor(m, o));
    float sum = 0.f;
    for (int i = start + lane; i < end; i += 64) {
        const float e = __expf(w[i] - m);
        w[i] = e;
        sum += e;
    }
#pragma unroll
    for (int o = 32; o; o >>= 1) sum += __shfl_xor(sum, o);
    if (lane == 0) rcp[n] = 1.f / (sum + 1e-16f);
}

// ---------------- aggregation: fp16 gathers, half2-paired heads ----------------
// Lane c: half2 at halfword 2c (heads 0/1) + halfword 128+2c (heads 2/3).
// 2x256B requests per edge; 4-edge unroll -> 8 gathers in flight.
template <bool RELU>
__global__ __launch_bounds__(256) void agg4_kernel(const _Float16* __restrict__ h,
                                                   const float* __restrict__ w,
                                                   const float* __restrict__ rcp,
                                                   const int* __restrict__ offs,
                                                   const int* __restrict__ csr,
                                                   const float* __restrict__ bias,
                                                   float* __restrict__ out, int n_nodes) {
    const int n = (blockIdx.x * blockDim.x + threadIdx.x) >> 6;
    const int c = threadIdx.x & 63;
    if (n >= n_nodes) return;
    const int start = offs[n];
    const int end = offs[n + 1];
    const bool lo32 = c < 32;

    float aLx = 0.f, aLy = 0.f, aHx = 0.f, aHy = 0.f;
    int i = start;
    for (; i + 3 < end; i += 4) {
#pragma unroll
        for (int u = 0; u < 4; ++u) {
            const int s = csr[i + u];
            const float4 we = *reinterpret_cast<const float4*>(&w[(size_t)(i + u) * 4]);
            const __half2* b = reinterpret_cast<const __half2*>(&h[(size_t)s * 256]);
            const float2 f0 = __half22float2(b[c]);
            const float2 f1 = __half22float2(b[64 + c]);
            const float wL = lo32 ? we.x : we.y;
            const float wH = lo32 ? we.z : we.w;
            aLx = fmaf(wL, f0.x, aLx);
            aLy = fmaf(wL, f0.y, aLy);
            aHx = fmaf(wH, f1.x, aHx);
            aHy = fmaf(wH, f1.y, aHy);
        }
    }
    for (; i < end; ++i) {
        const int s = csr[i];
        const float4 we = *reinterpret_cast<const float4*>(&w[(size_t)i * 4]);
        const __half2* b = reinterpret_cast<const __half2*>(&h[(size_t)s * 256]);
        const float2 f0 = __half22float2(b[c]);
        const float2 f1 = __half22float2(b[64 + c]);
        const float wL = lo32 ? we.x : we.y;
        const float wH = lo32 ? we.z : we.w;
        aLx = fmaf(wL, f0.x, aLx);
        aLy = fmaf(wL, f0.y, aLy);
        aHx = fmaf(wH, f1.x, aHx);
        aHy = fmaf(wH, f1.y, aHy);
    }
    const float4 r = *reinterpret_cast<const float4*>(&rcp[(size_t)n * 4]);
    const float rL = lo32 ? r.x : r.y;
    const float rH = lo32 ? r.z : r.w;
    float2 oL, oH;
    oL.x = aLx * rL + bias[2 * c];
    oL.y = aLy * rL + bias[2 * c + 1];
    oH.x = aHx * rH + bias[128 + 2 * c];
    oH.y = aHy * rH + bias[128 + 2 * c + 1];
    if (RELU) {
        oL.x = fmaxf(oL.x, 0.f);
        oL.y = fmaxf(oL.y, 0.f);
        oH.x = fmaxf(oH.x, 0.f);
        oH.y = fmaxf(oH.y, 0.f);
    }
    *reinterpret_cast<float2*>(&out[(size_t)n * 256 + 2 * c]) = oL;
    *reinterpret_cast<float2*>(&out[(size_t)n * 256 + 128 + 2 * c]) = oH;
}

template <bool RELU>
__global__ __launch_bounds__(256) void agg1_kernel(const _Float16* __restrict__ h,
                                                   const float* __restrict__ w,
                                                   const float* __restrict__ rcp,
                                                   const int* __restrict__ offs,
                                                   const int* __restrict__ csr,
                                                   const float* __restrict__ bias,
                                                   float* __restrict__ out, int n_nodes) {
    const int n = (blockIdx.x * blockDim.x + threadIdx.x) >> 6;
    const int c = threadIdx.x & 63;
    if (n >= n_nodes) return;
    const int start = offs[n];
    const int end = offs[n + 1];

    float acc0 = 0.f, acc1 = 0.f, acc2 = 0.f, acc3 = 0.f;
    int i = start;
    for (; i + 3 < end; i += 4) {
        const int s0 = csr[i], s1 = csr[i + 1], s2 = csr[i + 2], s3 = csr[i + 3];
        const float w0 = w[i], w1 = w[i + 1], w2 = w[i + 2], w3 = w[i + 3];
        acc0 = fmaf(w0, (float)h[(size_t)s0 * 64 + c], acc0);
        acc1 = fmaf(w1, (float)h[(size_t)s1 * 64 + c], acc1);
        acc2 = fmaf(w2, (float)h[(size_t)s2 * 64 + c], acc2);
        acc3 = fmaf(w3, (float)h[(size_t)s3 * 64 + c], acc3);
    }
    for (; i < end; ++i) {
        acc0 = fmaf(w[i], (float)h[(size_t)csr[i] * 64 + c], acc0);
    }
    float o = (acc0 + acc1 + acc2 + acc3) * rcp[n] + bias[c];
    if (RELU) o = fmaxf(o, 0.f);
    out[(size_t)n * 64 + c] = o;
}

// ---------------- launch ----------------
extern "C" void kernel_launch(void* const* d_in, const int* in_sizes, int n_in,
                              void* d_out, int out_size, void* d_ws, size_t ws_size,
                              hipStream_t stream) {
    const float* x   = (const float*)d_in[0];
    const int*   ei  = (const int*)d_in[1];
    const float* W1  = (const float*)d_in[2];
    const float* a1s = (const float*)d_in[3];
    const float* a1d = (const float*)d_in[4];
    const float* b1  = (const float*)d_in[5];
    const float* W2  = (const float*)d_in[6];
    const float* a2s = (const float*)d_in[7];
    const float* a2d = (const float*)d_in[8];
    const float* b2  = (const float*)d_in[9];
    const float* W3  = (const float*)d_in[10];
    const float* a3s = (const float*)d_in[11];
    const float* a3d = (const float*)d_in[12];
    const float* b3  = (const float*)d_in[13];
    float* out = (float*)d_out;

    const int N = in_sizes[0] / HID;
    const int E = in_sizes[1] / 2;
    const int* src = ei;
    const int* dst = ei + E;

    char* p = (char*)d_ws;
    auto alloc = [&](size_t bytes) {
        char* q = p;
        p += (bytes + 255) & ~(size_t)255;
        return q;
    };
    float* bufA = (float*)alloc((size_t)N * 256 * 4);
    float* bufB = (float*)alloc((size_t)N * 256 * 4);
    _Float16* h16 = (_Float16*)alloc((size_t)N * 256 * 2);
    float* alpS = (float*)alloc((size_t)N * NHEADS * 4);
    float* alpD = (float*)alloc((size_t)N * NHEADS * 4);
    float* wbuf = (float*)alloc((size_t)E * NHEADS * 4);
    float* rcp  = (float*)alloc((size_t)N * NHEADS * 4);
    int* counts = (int*)alloc((size_t)N * 4);
    int* offs   = (int*)alloc((size_t)(N + 1) * 4);
    int* wp     = (int*)alloc((size_t)N * 4);
    int* csr    = (int*)alloc((size_t)E * 4);
    int* bsum   = (int*)alloc((size_t)256 * 4);
    unsigned short* wt1h = (unsigned short*)alloc((size_t)64 * 256 * 2);
    unsigned short* wt1l = (unsigned short*)alloc((size_t)64 * 256 * 2);
    unsigned short* wt2h = (unsigned short*)alloc((size_t)256 * 256 * 2);
    unsigned short* wt2l = (unsigned short*)alloc((size_t)256 * 256 * 2);
    unsigned short* wt3h = (unsigned short*)alloc((size_t)256 * 64 * 2);
    unsigned short* wt3l = (unsigned short*)alloc((size_t)256 * 64 * 2);

    wsplit_kernel<<<(64 * 256 + 255) / 256, 256, 0, stream>>>(W1, wt1h, wt1l, 64, 256);
    wsplit_kernel<<<(256 * 256 + 255) / 256, 256, 0, stream>>>(W2, wt2h, wt2l, 256, 256);
    wsplit_kernel<<<(256 * 64 + 255) / 256, 256, 0, stream>>>(W3, wt3h, wt3l, 256, 64);

    hipMemsetAsync(counts, 0, (size_t)N * 4, stream);
    const int eb = (E + 255) / 256;
    const int nb = (N + 255) / 256;
    histo_kernel<<<eb, 256, 0, stream>>>(dst, counts, E);
    scanA_kernel<<<nb, 256, 0, stream>>>(counts, bsum, N);
    scanB_kernel<<<1, 256, 0, stream>>>(bsum, nb);
    scanC_kernel<<<nb, 256, 0, stream>>>(counts, bsum, offs, wp, N);
    scatter_kernel<<<eb, 256, 0, stream>>>(src, dst, wp, csr, E);

    const int gb64 = (N + 63) / 64;
    const int nwb = (N * 64 + 255) / 256;

    // layer 1: x[N,64] @ W1[64,256]
    gemm_mfma_kernel<64, 256, 128><<<dim3(gb64, 2), 256, 0, stream>>>(x, wt1h, wt1l, bufA, h16, N);
    alpha_kernel<<<(N * NHEADS * 64 + 255) / 256, 256, 0, stream>>>(bufA, a1s, a1d, alpS, alpD, N, NHEADS);
    maxsum4_kernel<<<nwb, 256, 0, stream>>>(alpS, alpD, offs, csr, wbuf, rcp, N);
    agg4_kernel<true><<<nwb, 256, 0, stream>>>(h16, wbuf, rcp, offs, csr, b1, bufB, N);

    // layer 2: bufB[N,256] @ W2[256,256]
    gemm_mfma_kernel<256, 256, 128><<<dim3(gb64, 2), 256, 0, stream>>>(bufB, wt2h, wt2l, bufA, h16, N);
    alpha_kernel<<<(N * NHEADS * 64 + 255) / 256, 256, 0, stream>>>(bufA, a2s, a2d, alpS, alpD, N, NHEADS);
    maxsum4_kernel<<<nwb, 256, 0, stream>>>(alpS, alpD, offs, csr, wbuf, rcp, N);
    agg4_kernel<true><<<nwb, 256, 0, stream>>>(h16, wbuf, rcp, offs, csr, b2, bufB, N);

    // layer 3: bufB[N,256] @ W3[256,64]
    gemm_mfma_kernel<256, 64, 64><<<dim3(gb64, 1), 256, 0, stream>>>(bufB, wt3h, wt3l, bufA, h16, N);
    alpha_kernel<<<(N * 1 * 64 + 255) / 256, 256, 0, stream>>>(bufA, a3s, a3d, alpS, alpD, N, 1);
    maxsum1_kernel<<<nwb, 256, 0, stream>>>(alpS, alpD, offs, csr, wbuf, rcp, N);
    agg1_kernel<false><<<nwb, 256, 0, stream>>>(h16, wbuf, rcp, offs, csr, b3, out, N);
}

// Round 9
// 202.279 us; speedup vs baseline: 2.1248x; 1.1815x over previous
//
#include <hip/hip_runtime.h>
#include <hip/hip_bf16.h>
#include <hip/hip_fp16.h>
#include <cstdint>

#define HID 64
#define NHEADS 4
#define NEG_SLOPE 0.2f

typedef __attribute__((ext_vector_type(8))) short short8;
typedef __attribute__((ext_vector_type(16))) float f32x16;
typedef unsigned short us;

__device__ __forceinline__ us f2bf(float f) {
    unsigned int u = __float_as_uint(f);
    unsigned int r = (u + 0x7FFFu + ((u >> 16) & 1u)) >> 16;
    return (us)r;
}
__device__ __forceinline__ float bf2f(us h) {
    return __uint_as_float(((unsigned int)h) << 16);
}
__device__ __forceinline__ float leaky(float e) {
    return (e > 0.f) ? e : NEG_SLOPE * e;
}

// ---------------- CSR build ----------------
__global__ void histo_kernel(const int* __restrict__ dst, int* __restrict__ counts, int E) {
    int i = blockIdx.x * blockDim.x + threadIdx.x;
    if (i < E) atomicAdd(&counts[dst[i]], 1);
}

__global__ __launch_bounds__(256) void scanA_kernel(const int* __restrict__ counts,
                                                    int* __restrict__ bsum, int n) {
    const int i = blockIdx.x * 256 + threadIdx.x;
    int v = (i < n) ? counts[i] : 0;
#pragma unroll
    for (int o = 32; o; o >>= 1) v += __shfl_xor(v, o);
    __shared__ int ws[4];
    if ((threadIdx.x & 63) == 0) ws[threadIdx.x >> 6] = v;
    __syncthreads();
    if (threadIdx.x == 0) bsum[blockIdx.x] = ws[0] + ws[1] + ws[2] + ws[3];
}

__global__ __launch_bounds__(256) void scanB_kernel(int* __restrict__ bsum, int nb) {
    __shared__ int sh[256];
    const int t = threadIdx.x;
    const int v = (t < nb) ? bsum[t] : 0;
    sh[t] = v;
    __syncthreads();
    for (int o = 1; o < 256; o <<= 1) {
        int u = (t >= o) ? sh[t - o] : 0;
        __syncthreads();
        sh[t] += u;
        __syncthreads();
    }
    if (t < nb) bsum[t] = sh[t] - v;
}

__global__ __launch_bounds__(256) void scanC_kernel(const int* __restrict__ counts,
                                                    const int* __restrict__ bsum,
                                                    int* __restrict__ offs,
                                                    int* __restrict__ wp, int n) {
    __shared__ int sh[256];
    const int t = threadIdx.x;
    const int i = blockIdx.x * 256 + t;
    const int v = (i < n) ? counts[i] : 0;
    sh[t] = v;
    __syncthreads();
    for (int o = 1; o < 256; o <<= 1) {
        int u = (t >= o) ? sh[t - o] : 0;
        __syncthreads();
        sh[t] += u;
        __syncthreads();
    }
    const int base = bsum[blockIdx.x];
    if (i < n) {
        const int off = base + sh[t] - v;
        offs[i] = off;
        wp[i] = off;
        if (i == n - 1) offs[n] = base + sh[t];
    }
}

__global__ void scatter_kernel(const int* __restrict__ src, const int* __restrict__ dst,
                               int* __restrict__ wp, int* __restrict__ csr, int E) {
    int i = blockIdx.x * blockDim.x + threadIdx.x;
    if (i < E) {
        int d = dst[i];
        int p = atomicAdd(&wp[d], 1);
        csr[p] = src[i];
    }
}

// ---------------- prep: W split (3x) + va = W@a precompute (3x) ----------------
__device__ __forceinline__ void wsplit_one(const float* __restrict__ W, us* __restrict__ WTh,
                                           us* __restrict__ WTl, int K, int OUTC, int i) {
    const int c = i / K;
    const int k = i - c * K;
    const float v = W[(size_t)k * OUTC + c];
    const us h = f2bf(v);
    WTh[i] = h;
    WTl[i] = f2bf(v - bf2f(h));
}

// vaT[j*K + k]: j<4 -> head j with a_src; j>=4 -> head j-4 with a_dst. bf16 hi/lo split.
__device__ __forceinline__ void vaprep_one(const float* __restrict__ W,
                                           const float* __restrict__ as,
                                           const float* __restrict__ ad,
                                           us* __restrict__ vh, us* __restrict__ vl,
                                           int K, int OUTC, int H, int i) {
    const int j = i / K;
    const int k = i - j * K;
    const int hh = (j < 4) ? j : j - 4;
    const float* a = (j < 4) ? as : ad;
    float acc = 0.f;
    if (hh < H) {
        for (int c = 0; c < 64; ++c)
            acc += W[(size_t)k * OUTC + hh * 64 + c] * a[hh * 64 + c];
    }
    const us h = f2bf(acc);
    vh[i] = h;
    vl[i] = f2bf(acc - bf2f(h));
}

__global__ __launch_bounds__(256) void prep_kernel(
    const float* W1, const float* W2, const float* W3,
    const float* a1s, const float* a1d, const float* a2s, const float* a2d,
    const float* a3s, const float* a3d,
    us* wt1h, us* wt1l, us* wt2h, us* wt2l, us* wt3h, us* wt3l,
    us* va1h, us* va1l, us* va2h, us* va2l, us* va3h, us* va3l) {
    int idx = blockIdx.x * 256 + threadIdx.x;
    if (idx < 16384) { wsplit_one(W1, wt1h, wt1l, 64, 256, idx); return; }
    idx -= 16384;
    if (idx < 65536) { wsplit_one(W2, wt2h, wt2l, 256, 256, idx); return; }
    idx -= 65536;
    if (idx < 16384) { wsplit_one(W3, wt3h, wt3l, 256, 64, idx); return; }
    idx -= 16384;
    if (idx < 512) { vaprep_one(W1, a1s, a1d, va1h, va1l, 64, 256, 4, idx); return; }
    idx -= 512;
    if (idx < 2048) { vaprep_one(W2, a2s, a2d, va2h, va2l, 256, 256, 4, idx); return; }
    idx -= 2048;
    if (idx < 2048) { vaprep_one(W3, a3s, a3d, va3h, va3l, 256, 64, 1, idx); return; }
}

// ---------------- GEMM via MFMA split-bf16 + fused MFMA alpha ----------------
// Output: h16 (fp16) only + alpha_s/alpha_d via extra B-tile (va = W@a).
template <int K, int OUTC, int BN, int HA>
__global__ __launch_bounds__(256) void gemm_mfma_kernel(const float* __restrict__ X,
                                                        const us* __restrict__ WTh,
                                                        const us* __restrict__ WTl,
                                                        const us* __restrict__ vah,
                                                        const us* __restrict__ val,
                                                        _Float16* __restrict__ H16,
                                                        float* __restrict__ alpha_s,
                                                        float* __restrict__ alpha_d, int nrows) {
    constexpr int CGS = BN / 64;
    constexpr int NB = BN / 64;
    constexpr int TPC = 4 / NB;
    __shared__ short Ah[64 * 32];
    __shared__ short Al[64 * 32];
    __shared__ short Bh[BN * 32];
    __shared__ short Bl[BN * 32];
    __shared__ short Vh[8 * 32];
    __shared__ short Vl[8 * 32];

    const int tid = threadIdx.x;
    const int lane = tid & 63;
    const int wid = tid >> 6;
    const int wr = wid >> 1;
    const int wc = wid & 1;
    const int r31 = lane & 31;
    const int khw = lane >> 5;
    const int row0 = blockIdx.x * 64;
    const int c0 = blockIdx.y * BN;
    const bool alpha_blk = (blockIdx.y == 0);
    const bool alpha_wave = alpha_blk && (wc == 0);

    const int ar = tid >> 2;
    const int akq = (tid & 3) * 8;
    const int arow = row0 + ar;
    const bool aok = arow < nrows;

    const int bcol = tid / TPC;
    const int bkb = (tid % TPC) * NB;

    f32x16 acc[CGS];
#pragma unroll
    for (int cg = 0; cg < CGS; ++cg)
#pragma unroll
        for (int r = 0; r < 16; ++r) acc[cg][r] = 0.f;
    f32x16 accv;
#pragma unroll
    for (int r = 0; r < 16; ++r) accv[r] = 0.f;

    for (int k0 = 0; k0 < K; k0 += 32) {
        __syncthreads();
        {
            float4 v0 = make_float4(0.f, 0.f, 0.f, 0.f), v1 = v0;
            if (aok) {
                v0 = *reinterpret_cast<const float4*>(&X[(size_t)arow * K + k0 + akq]);
                v1 = *reinterpret_cast<const float4*>(&X[(size_t)arow * K + k0 + akq + 4]);
            }
            float vs[8] = {v0.x, v0.y, v0.z, v0.w, v1.x, v1.y, v1.z, v1.w};
            short8 hi, lo;
#pragma unroll
            for (int j = 0; j < 8; ++j) {
                us h = f2bf(vs[j]);
                hi[j] = (short)h;
                lo[j] = (short)f2bf(vs[j] - bf2f(h));
            }
            const int blk = (akq >> 3) ^ (ar & 3);
            const int off = ar * 32 + (blk << 3);
            *reinterpret_cast<short8*>(&Ah[off]) = hi;
            *reinterpret_cast<short8*>(&Al[off]) = lo;
        }
        {
            const us* srcH = &WTh[(size_t)(c0 + bcol) * K + k0 + bkb * 8];
            const us* srcL = &WTl[(size_t)(c0 + bcol) * K + k0 + bkb * 8];
#pragma unroll
            for (int b = 0; b < NB; ++b) {
                short8 h = *reinterpret_cast<const short8*>(&srcH[b * 8]);
                short8 l = *reinterpret_cast<const short8*>(&srcL[b * 8]);
                const int blk = (bkb + b) ^ (bcol & 3);
                const int off = bcol * 32 + (blk << 3);
                *reinterpret_cast<short8*>(&Bh[off]) = h;
                *reinterpret_cast<short8*>(&Bl[off]) = l;
            }
        }
        if (alpha_blk && tid < 32) {
            const int col = tid >> 2, kb2 = tid & 3;
            *reinterpret_cast<short8*>(&Vh[col * 32 + kb2 * 8]) =
                *reinterpret_cast<const short8*>(&vah[col * K + k0 + kb2 * 8]);
            *reinterpret_cast<short8*>(&Vl[col * 32 + kb2 * 8]) =
                *reinterpret_cast<const short8*>(&val[col * K + k0 + kb2 * 8]);
        }
        __syncthreads();
#pragma unroll
        for (int ks = 0; ks < 32; ks += 16) {
            const int kb = (ks >> 3) + khw;
            const int aoff = (wr * 32 + r31) * 32 + ((kb ^ (r31 & 3)) << 3);
            short8 ah = *reinterpret_cast<const short8*>(&Ah[aoff]);
            short8 al = *reinterpret_cast<const short8*>(&Al[aoff]);
#pragma unroll
            for (int cg = 0; cg < CGS; ++cg) {
                const int coll = wc * (BN / 2) + cg * 32 + r31;
                const int boff = coll * 32 + ((kb ^ (r31 & 3)) << 3);
                short8 bh = *reinterpret_cast<const short8*>(&Bh[boff]);
                short8 bl = *reinterpret_cast<const short8*>(&Bl[boff]);
                acc[cg] = __builtin_amdgcn_mfma_f32_32x32x16_bf16(ah, bh, acc[cg], 0, 0, 0);
                acc[cg] = __builtin_amdgcn_mfma_f32_32x32x16_bf16(ah, bl, acc[cg], 0, 0, 0);
                acc[cg] = __builtin_amdgcn_mfma_f32_32x32x16_bf16(al, bh, acc[cg], 0, 0, 0);
            }
            if (alpha_wave) {
                short8 vh = {}, vl = {};
                if (r31 < 8) {
                    vh = *reinterpret_cast<const short8*>(&Vh[r31 * 32 + (kb << 3)]);
                    vl = *reinterpret_cast<const short8*>(&Vl[r31 * 32 + (kb << 3)]);
                }
                accv = __builtin_amdgcn_mfma_f32_32x32x16_bf16(ah, vh, accv, 0, 0, 0);
                accv = __builtin_amdgcn_mfma_f32_32x32x16_bf16(ah, vl, accv, 0, 0, 0);
                accv = __builtin_amdgcn_mfma_f32_32x32x16_bf16(al, vh, accv, 0, 0, 0);
            }
        }
    }

    // epilogue: h16 + alpha (C/D layout: col=lane&31, row=(reg&3)+8*(reg>>2)+4*(lane>>5))
#pragma unroll
    for (int cg = 0; cg < CGS; ++cg) {
#pragma unroll
        for (int reg = 0; reg < 16; ++reg) {
            const int row = row0 + wr * 32 + (reg & 3) + 8 * (reg >> 2) + 4 * khw;
            if (row < nrows) {
                const int col = c0 + wc * (BN / 2) + cg * 32 + r31;
                H16[(size_t)row * OUTC + col] = (_Float16)acc[cg][reg];
            }
        }
    }
    if (alpha_wave && r31 < 8) {
        const int hsel = r31 & 3;
        if (hsel < HA) {
            float* dstp = (r31 < 4) ? alpha_s : alpha_d;
#pragma unroll
            for (int reg = 0; reg < 16; ++reg) {
                const int row = row0 + wr * 32 + (reg & 3) + 8 * (reg >> 2) + 4 * khw;
                if (row < nrows) dstp[(size_t)row * HA + hsel] = accv[reg];
            }
        }
    }
}

// ---------------- fused segment-softmax + aggregation, 4 heads ----------------
// One wave per node. Phase 1: lanes over edges -> w[i]=ex, rcp in regs.
// Phase 2: lanes over channels (head=lane>>4), one dwordx2 gather per edge per lane.
template <bool RELU>
__global__ __launch_bounds__(256) void maxagg4_kernel(const _Float16* __restrict__ h,
                                                      const float* __restrict__ alpha_s,
                                                      const float* __restrict__ alpha_d,
                                                      const int* __restrict__ offs,
                                                      const int* __restrict__ csr,
                                                      float* __restrict__ w,
                                                      const float* __restrict__ bias,
                                                      float* __restrict__ out, int n_nodes) {
    const int gw = (blockIdx.x * blockDim.x + threadIdx.x) >> 6;
    const int lane = threadIdx.x & 63;
    const bool valid = gw < n_nodes;
    int start = 0, end = 0;
    float4 r = make_float4(0.f, 0.f, 0.f, 0.f);
    if (valid) {
        start = offs[gw];
        end = offs[gw + 1];
        const float4 ad = *reinterpret_cast<const float4*>(&alpha_d[(size_t)gw * 4]);
        float4 m = make_float4(-INFINITY, -INFINITY, -INFINITY, -INFINITY);
        float4 sum = make_float4(0.f, 0.f, 0.f, 0.f);
        if (end - start <= 64) {
            const int i = start + lane;
            const bool has = i < end;
            float4 e;
            if (has) {
                const int s = csr[i];
                const float4 a = *reinterpret_cast<const float4*>(&alpha_s[(size_t)s * 4]);
                e.x = leaky(a.x + ad.x);
                e.y = leaky(a.y + ad.y);
                e.z = leaky(a.z + ad.z);
                e.w = leaky(a.w + ad.w);
                m = e;
            }
#pragma unroll
            for (int o = 32; o; o >>= 1) {
                m.x = fmaxf(m.x, __shfl_xor(m.x, o));
                m.y = fmaxf(m.y, __shfl_xor(m.y, o));
                m.z = fmaxf(m.z, __shfl_xor(m.z, o));
                m.w = fmaxf(m.w, __shfl_xor(m.w, o));
            }
            if (has) {
                float4 ex;
                ex.x = __expf(e.x - m.x);
                ex.y = __expf(e.y - m.y);
                ex.z = __expf(e.z - m.z);
                ex.w = __expf(e.w - m.w);
                *reinterpret_cast<float4*>(&w[(size_t)i * 4]) = ex;
                sum = ex;
            }
#pragma unroll
            for (int o = 32; o; o >>= 1) {
                sum.x += __shfl_xor(sum.x, o);
                sum.y += __shfl_xor(sum.y, o);
                sum.z += __shfl_xor(sum.z, o);
                sum.w += __shfl_xor(sum.w, o);
            }
        } else {
            for (int i = start + lane; i < end; i += 64) {
                const int s = csr[i];
                const float4 a = *reinterpret_cast<const float4*>(&alpha_s[(size_t)s * 4]);
                float4 e;
                e.x = leaky(a.x + ad.x);
                e.y = leaky(a.y + ad.y);
                e.z = leaky(a.z + ad.z);
                e.w = leaky(a.w + ad.w);
                *reinterpret_cast<float4*>(&w[(size_t)i * 4]) = e;
                m.x = fmaxf(m.x, e.x);
                m.y = fmaxf(m.y, e.y);
                m.z = fmaxf(m.z, e.z);
                m.w = fmaxf(m.w, e.w);
            }
#pragma unroll
            for (int o = 32; o; o >>= 1) {
                m.x = fmaxf(m.x, __shfl_xor(m.x, o));
                m.y = fmaxf(m.y, __shfl_xor(m.y, o));
                m.z = fmaxf(m.z, __shfl_xor(m.z, o));
                m.w = fmaxf(m.w, __shfl_xor(m.w, o));
            }
            for (int i = start + lane; i < end; i += 64) {
                float4 e = *reinterpret_cast<float4*>(&w[(size_t)i * 4]);
                e.x = __expf(e.x - m.x);
                e.y = __expf(e.y - m.y);
                e.z = __expf(e.z - m.z);
                e.w = __expf(e.w - m.w);
                *reinterpret_cast<float4*>(&w[(size_t)i * 4]) = e;
                sum.x += e.x;
                sum.y += e.y;
                sum.z += e.z;
                sum.w += e.w;
            }
#pragma unroll
            for (int o = 32; o; o >>= 1) {
                sum.x += __shfl_xor(sum.x, o);
                sum.y += __shfl_xor(sum.y, o);
                sum.z += __shfl_xor(sum.z, o);
                sum.w += __shfl_xor(sum.w, o);
            }
        }
        r.x = 1.f / (sum.x + 1e-16f);
        r.y = 1.f / (sum.y + 1e-16f);
        r.z = 1.f / (sum.z + 1e-16f);
        r.w = 1.f / (sum.w + 1e-16f);
    }
    __syncthreads();
    if (!valid) return;

    const int head = lane >> 4;
    const int cb = lane << 2;  // channel base (0..252)
    float4 acc = make_float4(0.f, 0.f, 0.f, 0.f);
    int i = start;
    for (; i + 1 < end; i += 2) {
        const int s0 = csr[i];
        const int s1 = csr[i + 1];
        const float4 w0 = *reinterpret_cast<const float4*>(&w[(size_t)i * 4]);
        const float4 w1 = *reinterpret_cast<const float4*>(&w[(size_t)(i + 1) * 4]);
        const float wv0 = head == 0 ? w0.x : head == 1 ? w0.y : head == 2 ? w0.z : w0.w;
        const float wv1 = head == 0 ? w1.x : head == 1 ? w1.y : head == 2 ? w1.z : w1.w;
        const uint2 u0 = *reinterpret_cast<const uint2*>(&h[(size_t)s0 * 256 + cb]);
        const uint2 u1 = *reinterpret_cast<const uint2*>(&h[(size_t)s1 * 256 + cb]);
        const float2 f00 = __half22float2(__builtin_bit_cast(__half2, u0.x));
        const float2 f01 = __half22float2(__builtin_bit_cast(__half2, u0.y));
        const float2 f10 = __half22float2(__builtin_bit_cast(__half2, u1.x));
        const float2 f11 = __half22float2(__builtin_bit_cast(__half2, u1.y));
        acc.x = fmaf(wv0, f00.x, acc.x);
        acc.y = fmaf(wv0, f00.y, acc.y);
        acc.z = fmaf(wv0, f01.x, acc.z);
        acc.w = fmaf(wv0, f01.y, acc.w);
        acc.x = fmaf(wv1, f10.x, acc.x);
        acc.y = fmaf(wv1, f10.y, acc.y);
        acc.z = fmaf(wv1, f11.x, acc.z);
        acc.w = fmaf(wv1, f11.y, acc.w);
    }
    if (i < end) {
        const int s0 = csr[i];
        const float4 w0 = *reinterpret_cast<const float4*>(&w[(size_t)i * 4]);
        const float wv0 = head == 0 ? w0.x : head == 1 ? w0.y : head == 2 ? w0.z : w0.w;
        const uint2 u0 = *reinterpret_cast<const uint2*>(&h[(size_t)s0 * 256 + cb]);
        const float2 f00 = __half22float2(__builtin_bit_cast(__half2, u0.x));
        const float2 f01 = __half22float2(__builtin_bit_cast(__half2, u0.y));
        acc.x = fmaf(wv0, f00.x, acc.x);
        acc.y = fmaf(wv0, f00.y, acc.y);
        acc.z = fmaf(wv0, f01.x, acc.z);
        acc.w = fmaf(wv0, f01.y, acc.w);
    }
    const float rv = head == 0 ? r.x : head == 1 ? r.y : head == 2 ? r.z : r.w;
    const float4 b4 = *reinterpret_cast<const float4*>(&bias[cb]);
    float4 o;
    o.x = acc.x * rv + b4.x;
    o.y = acc.y * rv + b4.y;
    o.z = acc.z * rv + b4.z;
    o.w = acc.w * rv + b4.w;
    if (RELU) {
        o.x = fmaxf(o.x, 0.f);
        o.y = fmaxf(o.y, 0.f);
        o.z = fmaxf(o.z, 0.f);
        o.w = fmaxf(o.w, 0.f);
    }
    *reinterpret_cast<float4*>(&out[(size_t)gw * 256 + cb]) = o;
}

// ---------------- fused softmax + aggregation, 1 head ----------------
template <bool RELU>
__global__ __launch_bounds__(256) void maxagg1_kernel(const _Float16* __restrict__ h,
                                                      const float* __restrict__ alpha_s,
                                                      const float* __restrict__ alpha_d,
                                                      const int* __restrict__ offs,
                                                      const int* __restrict__ csr,
                                                      float* __restrict__ w,
                                                      const float* __restrict__ bias,
                                                      float* __restrict__ out, int n_nodes) {
    const int gw = (blockIdx.x * blockDim.x + threadIdx.x) >> 6;
    const int lane = threadIdx.x & 63;
    const bool valid = gw < n_nodes;
    int start = 0, end = 0;
    float r = 0.f;
    if (valid) {
        start = offs[gw];
        end = offs[gw + 1];
        const float ad = alpha_d[gw];
        float m = -INFINITY, sum = 0.f;
        if (end - start <= 64) {
            const int i = start + lane;
            const bool has = i < end;
            float e = 0.f;
            if (has) {
                e = leaky(alpha_s[csr[i]] + ad);
                m = e;
            }
#pragma unroll
            for (int o = 32; o; o >>= 1) m = fmaxf(m, __shfl_xor(m, o));
            if (has) {
                const float ex = __expf(e - m);
                w[i] = ex;
                sum = ex;
            }
#pragma unroll
            for (int o = 32; o; o >>= 1) sum += __shfl_xor(sum, o);
        } else {
            for (int i = start + lane; i < end; i += 64) {
                const float e = leaky(alpha_s[csr[i]] + ad);
                w[i] = e;
                m = fmaxf(m, e);
            }
#pragma unroll
            for (int o = 32; o; o >>= 1) m = fmaxf(m, __shfl_xor(m, o));
            for (int i = start + lane; i < end; i += 64) {
                const float ex = __expf(w[i] - m);
                w[i] = ex;
                sum += ex;
            }
#pragma unroll
            for (int o = 32; o; o >>= 1) sum += __shfl_xor(sum, o);
        }
        r = 1.f / (sum + 1e-16f);
    }
    __syncthreads();
    if (!valid) return;

    float acc0 = 0.f, acc1 = 0.f, acc2 = 0.f, acc3 = 0.f;
    int i = start;
    for (; i + 3 < end; i += 4) {
        const int s0 = csr[i], s1 = csr[i + 1], s2 = csr[i + 2], s3 = csr[i + 3];
        const float w0 = w[i], w1 = w[i + 1], w2 = w[i + 2], w3 = w[i + 3];
        acc0 = fmaf(w0, (float)h[(size_t)s0 * 64 + lane], acc0);
        acc1 = fmaf(w1, (float)h[(size_t)s1 * 64 + lane], acc1);
        acc2 = fmaf(w2, (float)h[(size_t)s2 * 64 + lane], acc2);
        acc3 = fmaf(w3, (float)h[(size_t)s3 * 64 + lane], acc3);
    }
    for (; i < end; ++i) acc0 = fmaf(w[i], (float)h[(size_t)csr[i] * 64 + lane], acc0);
    float o = (acc0 + acc1 + acc2 + acc3) * r + bias[lane];
    if (RELU) o = fmaxf(o, 0.f);
    out[(size_t)gw * 64 + lane] = o;
}

// ---------------- launch ----------------
extern "C" void kernel_launch(void* const* d_in, const int* in_sizes, int n_in,
                              void* d_out, int out_size, void* d_ws, size_t ws_size,
                              hipStream_t stream) {
    const float* x   = (const float*)d_in[0];
    const int*   ei  = (const int*)d_in[1];
    const float* W1  = (const float*)d_in[2];
    const float* a1s = (const float*)d_in[3];
    const float* a1d = (const float*)d_in[4];
    const float* b1  = (const float*)d_in[5];
    const float* W2  = (const float*)d_in[6];
    const float* a2s = (const float*)d_in[7];
    const float* a2d = (const float*)d_in[8];
    const float* b2  = (const float*)d_in[9];
    const float* W3  = (const float*)d_in[10];
    const float* a3s = (const float*)d_in[11];
    const float* a3d = (const float*)d_in[12];
    const float* b3  = (const float*)d_in[13];
    float* out = (float*)d_out;

    const int N = in_sizes[0] / HID;
    const int E = in_sizes[1] / 2;
    const int* src = ei;
    const int* dst = ei + E;

    char* p = (char*)d_ws;
    auto alloc = [&](size_t bytes) {
        char* q = p;
        p += (bytes + 255) & ~(size_t)255;
        return q;
    };
    float* bufA = (float*)alloc((size_t)N * 256 * 4);
    float* bufB = (float*)alloc((size_t)N * 256 * 4);
    _Float16* h16 = (_Float16*)alloc((size_t)N * 256 * 2);
    float* alpS = (float*)alloc((size_t)N * NHEADS * 4);
    float* alpD = (float*)alloc((size_t)N * NHEADS * 4);
    float* wbuf = (float*)alloc((size_t)E * NHEADS * 4);
    int* counts = (int*)alloc((size_t)N * 4);
    int* offs   = (int*)alloc((size_t)(N + 1) * 4);
    int* wp     = (int*)alloc((size_t)N * 4);
    int* csr    = (int*)alloc((size_t)E * 4);
    int* bsum   = (int*)alloc((size_t)256 * 4);
    us* wt1h = (us*)alloc((size_t)64 * 256 * 2);
    us* wt1l = (us*)alloc((size_t)64 * 256 * 2);
    us* wt2h = (us*)alloc((size_t)256 * 256 * 2);
    us* wt2l = (us*)alloc((size_t)256 * 256 * 2);
    us* wt3h = (us*)alloc((size_t)256 * 64 * 2);
    us* wt3l = (us*)alloc((size_t)256 * 64 * 2);
    us* va1h = (us*)alloc((size_t)8 * 64 * 2);
    us* va1l = (us*)alloc((size_t)8 * 64 * 2);
    us* va2h = (us*)alloc((size_t)8 * 256 * 2);
    us* va2l = (us*)alloc((size_t)8 * 256 * 2);
    us* va3h = (us*)alloc((size_t)8 * 256 * 2);
    us* va3l = (us*)alloc((size_t)8 * 256 * 2);

    hipMemsetAsync(counts, 0, (size_t)N * 4, stream);
    const int eb = (E + 255) / 256;
    const int nb = (N + 255) / 256;
    histo_kernel<<<eb, 256, 0, stream>>>(dst, counts, E);
    scanA_kernel<<<nb, 256, 0, stream>>>(counts, bsum, N);
    scanB_kernel<<<1, 256, 0, stream>>>(bsum, nb);
    scanC_kernel<<<nb, 256, 0, stream>>>(counts, bsum, offs, wp, N);
    scatter_kernel<<<eb, 256, 0, stream>>>(src, dst, wp, csr, E);

    // prep: 16384+65536+16384+512+2048+2048 = 102912 elems
    prep_kernel<<<(102912 + 255) / 256, 256, 0, stream>>>(
        W1, W2, W3, a1s, a1d, a2s, a2d, a3s, a3d,
        wt1h, wt1l, wt2h, wt2l, wt3h, wt3l,
        va1h, va1l, va2h, va2l, va3h, va3l);

    const int gb64 = (N + 63) / 64;
    const int nwb = (N * 64 + 255) / 256;

    // layer 1
    gemm_mfma_kernel<64, 256, 128, 4><<<dim3(gb64, 2), 256, 0, stream>>>(
        x, wt1h, wt1l, va1h, va1l, h16, alpS, alpD, N);
    maxagg4_kernel<true><<<nwb, 256, 0, stream>>>(h16, alpS, alpD, offs, csr, wbuf, b1, bufB, N);

    // layer 2
    gemm_mfma_kernel<256, 256, 128, 4><<<dim3(gb64, 2), 256, 0, stream>>>(
        bufB, wt2h, wt2l, va2h, va2l, h16, alpS, alpD, N);
    maxagg4_kernel<true><<<nwb, 256, 0, stream>>>(h16, alpS, alpD, offs, csr, wbuf, b2, bufA, N);

    // layer 3
    gemm_mfma_kernel<256, 64, 64, 1><<<dim3(gb64, 1), 256, 0, stream>>>(
        bufA, wt3h, wt3l, va3h, va3l, h16, alpS, alpD, N);
    maxagg1_kernel<false><<<nwb, 256, 0, stream>>>(h16, alpS, alpD, offs, csr, wbuf, b3, out, N);
}

// Round 10
// 171.654 us; speedup vs baseline: 2.5039x; 1.1784x over previous
//
#include <hip/hip_runtime.h>
#include <hip/hip_bf16.h>
#include <hip/hip_fp16.h>
#include <cstdint>

#define HID 64
#define NHEADS 4
#define NEG_SLOPE 0.2f

typedef __attribute__((ext_vector_type(8))) short short8;
typedef __attribute__((ext_vector_type(16))) float f32x16;
typedef unsigned short us;

__device__ __forceinline__ us f2bf(float f) {
    unsigned int u = __float_as_uint(f);
    unsigned int r = (u + 0x7FFFu + ((u >> 16) & 1u)) >> 16;
    return (us)r;
}
__device__ __forceinline__ float bf2f(us h) {
    return __uint_as_float(((unsigned int)h) << 16);
}
__device__ __forceinline__ float leaky(float e) {
    return (e > 0.f) ? e : NEG_SLOPE * e;
}

// ---------------- CSR build ----------------
__global__ void histo_kernel(const int* __restrict__ dst, int* __restrict__ counts, int E) {
    int i = blockIdx.x * blockDim.x + threadIdx.x;
    if (i < E) atomicAdd(&counts[dst[i]], 1);
}

__global__ __launch_bounds__(256) void scanA_kernel(const int* __restrict__ counts,
                                                    int* __restrict__ bsum, int n) {
    const int i = blockIdx.x * 256 + threadIdx.x;
    int v = (i < n) ? counts[i] : 0;
#pragma unroll
    for (int o = 32; o; o >>= 1) v += __shfl_xor(v, o);
    __shared__ int ws[4];
    if ((threadIdx.x & 63) == 0) ws[threadIdx.x >> 6] = v;
    __syncthreads();
    if (threadIdx.x == 0) bsum[blockIdx.x] = ws[0] + ws[1] + ws[2] + ws[3];
}

__global__ __launch_bounds__(256) void scanB_kernel(int* __restrict__ bsum, int nb) {
    __shared__ int sh[256];
    const int t = threadIdx.x;
    const int v = (t < nb) ? bsum[t] : 0;
    sh[t] = v;
    __syncthreads();
    for (int o = 1; o < 256; o <<= 1) {
        int u = (t >= o) ? sh[t - o] : 0;
        __syncthreads();
        sh[t] += u;
        __syncthreads();
    }
    if (t < nb) bsum[t] = sh[t] - v;
}

__global__ __launch_bounds__(256) void scanC_kernel(const int* __restrict__ counts,
                                                    const int* __restrict__ bsum,
                                                    int* __restrict__ offs,
                                                    int* __restrict__ wp, int n) {
    __shared__ int sh[256];
    const int t = threadIdx.x;
    const int i = blockIdx.x * 256 + t;
    const int v = (i < n) ? counts[i] : 0;
    sh[t] = v;
    __syncthreads();
    for (int o = 1; o < 256; o <<= 1) {
        int u = (t >= o) ? sh[t - o] : 0;
        __syncthreads();
        sh[t] += u;
        __syncthreads();
    }
    const int base = bsum[blockIdx.x];
    if (i < n) {
        const int off = base + sh[t] - v;
        offs[i] = off;
        wp[i] = off;
        if (i == n - 1) offs[n] = base + sh[t];
    }
}

__global__ void scatter_kernel(const int* __restrict__ src, const int* __restrict__ dst,
                               int* __restrict__ wp, int* __restrict__ csr, int E) {
    int i = blockIdx.x * blockDim.x + threadIdx.x;
    if (i < E) {
        int d = dst[i];
        int p = atomicAdd(&wp[d], 1);
        csr[p] = src[i];
    }
}

// ---------------- prep: W split (3x) + va = W@a precompute (3x) ----------------
__device__ __forceinline__ void wsplit_one(const float* __restrict__ W, us* __restrict__ WTh,
                                           us* __restrict__ WTl, int K, int OUTC, int i) {
    const int c = i / K;
    const int k = i - c * K;
    const float v = W[(size_t)k * OUTC + c];
    const us h = f2bf(v);
    WTh[i] = h;
    WTl[i] = f2bf(v - bf2f(h));
}

__device__ __forceinline__ void vaprep_one(const float* __restrict__ W,
                                           const float* __restrict__ as,
                                           const float* __restrict__ ad,
                                           us* __restrict__ vh, us* __restrict__ vl,
                                           int K, int OUTC, int H, int i) {
    const int j = i / K;
    const int k = i - j * K;
    const int hh = (j < 4) ? j : j - 4;
    const float* a = (j < 4) ? as : ad;
    float acc = 0.f;
    if (hh < H) {
        for (int c = 0; c < 64; ++c)
            acc += W[(size_t)k * OUTC + hh * 64 + c] * a[hh * 64 + c];
    }
    const us h = f2bf(acc);
    vh[i] = h;
    vl[i] = f2bf(acc - bf2f(h));
}

__global__ __launch_bounds__(256) void prep_kernel(
    const float* W1, const float* W2, const float* W3,
    const float* a1s, const float* a1d, const float* a2s, const float* a2d,
    const float* a3s, const float* a3d,
    us* wt1h, us* wt1l, us* wt2h, us* wt2l, us* wt3h, us* wt3l,
    us* va1h, us* va1l, us* va2h, us* va2l, us* va3h, us* va3l) {
    int idx = blockIdx.x * 256 + threadIdx.x;
    if (idx < 16384) { wsplit_one(W1, wt1h, wt1l, 64, 256, idx); return; }
    idx -= 16384;
    if (idx < 65536) { wsplit_one(W2, wt2h, wt2l, 256, 256, idx); return; }
    idx -= 65536;
    if (idx < 16384) { wsplit_one(W3, wt3h, wt3l, 256, 64, idx); return; }
    idx -= 16384;
    if (idx < 512) { vaprep_one(W1, a1s, a1d, va1h, va1l, 64, 256, 4, idx); return; }
    idx -= 512;
    if (idx < 2048) { vaprep_one(W2, a2s, a2d, va2h, va2l, 256, 256, 4, idx); return; }
    idx -= 2048;
    if (idx < 2048) { vaprep_one(W3, a3s, a3d, va3h, va3l, 256, 64, 1, idx); return; }
}

// ---------------- GEMM via MFMA split-bf16 + fused MFMA alpha ----------------
template <int K, int OUTC, int BN, int HA>
__global__ __launch_bounds__(256) void gemm_mfma_kernel(const float* __restrict__ X,
                                                        const us* __restrict__ WTh,
                                                        const us* __restrict__ WTl,
                                                        const us* __restrict__ vah,
                                                        const us* __restrict__ val,
                                                        _Float16* __restrict__ H16,
                                                        float* __restrict__ alpha_s,
                                                        float* __restrict__ alpha_d, int nrows) {
    constexpr int CGS = BN / 64;
    constexpr int NB = BN / 64;
    constexpr int TPC = 4 / NB;
    __shared__ short Ah[64 * 32];
    __shared__ short Al[64 * 32];
    __shared__ short Bh[BN * 32];
    __shared__ short Bl[BN * 32];
    __shared__ short Vh[8 * 32];
    __shared__ short Vl[8 * 32];

    const int tid = threadIdx.x;
    const int lane = tid & 63;
    const int wid = tid >> 6;
    const int wr = wid >> 1;
    const int wc = wid & 1;
    const int r31 = lane & 31;
    const int khw = lane >> 5;
    const int row0 = blockIdx.x * 64;
    const int c0 = blockIdx.y * BN;
    const bool alpha_blk = (blockIdx.y == 0);
    const bool alpha_wave = alpha_blk && (wc == 0);

    const int ar = tid >> 2;
    const int akq = (tid & 3) * 8;
    const int arow = row0 + ar;
    const bool aok = arow < nrows;

    const int bcol = tid / TPC;
    const int bkb = (tid % TPC) * NB;

    f32x16 acc[CGS];
#pragma unroll
    for (int cg = 0; cg < CGS; ++cg)
#pragma unroll
        for (int r = 0; r < 16; ++r) acc[cg][r] = 0.f;
    f32x16 accv;
#pragma unroll
    for (int r = 0; r < 16; ++r) accv[r] = 0.f;

    for (int k0 = 0; k0 < K; k0 += 32) {
        __syncthreads();
        {
            float4 v0 = make_float4(0.f, 0.f, 0.f, 0.f), v1 = v0;
            if (aok) {
                v0 = *reinterpret_cast<const float4*>(&X[(size_t)arow * K + k0 + akq]);
                v1 = *reinterpret_cast<const float4*>(&X[(size_t)arow * K + k0 + akq + 4]);
            }
            float vs[8] = {v0.x, v0.y, v0.z, v0.w, v1.x, v1.y, v1.z, v1.w};
            short8 hi, lo;
#pragma unroll
            for (int j = 0; j < 8; ++j) {
                us h = f2bf(vs[j]);
                hi[j] = (short)h;
                lo[j] = (short)f2bf(vs[j] - bf2f(h));
            }
            const int blk = (akq >> 3) ^ (ar & 3);
            const int off = ar * 32 + (blk << 3);
            *reinterpret_cast<short8*>(&Ah[off]) = hi;
            *reinterpret_cast<short8*>(&Al[off]) = lo;
        }
        {
            const us* srcH = &WTh[(size_t)(c0 + bcol) * K + k0 + bkb * 8];
            const us* srcL = &WTl[(size_t)(c0 + bcol) * K + k0 + bkb * 8];
#pragma unroll
            for (int b = 0; b < NB; ++b) {
                short8 h = *reinterpret_cast<const short8*>(&srcH[b * 8]);
                short8 l = *reinterpret_cast<const short8*>(&srcL[b * 8]);
                const int blk = (bkb + b) ^ (bcol & 3);
                const int off = bcol * 32 + (blk << 3);
                *reinterpret_cast<short8*>(&Bh[off]) = h;
                *reinterpret_cast<short8*>(&Bl[off]) = l;
            }
        }
        if (alpha_blk && tid < 32) {
            const int col = tid >> 2, kb2 = tid & 3;
            *reinterpret_cast<short8*>(&Vh[col * 32 + kb2 * 8]) =
                *reinterpret_cast<const short8*>(&vah[col * K + k0 + kb2 * 8]);
            *reinterpret_cast<short8*>(&Vl[col * 32 + kb2 * 8]) =
                *reinterpret_cast<const short8*>(&val[col * K + k0 + kb2 * 8]);
        }
        __syncthreads();
#pragma unroll
        for (int ks = 0; ks < 32; ks += 16) {
            const int kb = (ks >> 3) + khw;
            const int aoff = (wr * 32 + r31) * 32 + ((kb ^ (r31 & 3)) << 3);
            short8 ah = *reinterpret_cast<const short8*>(&Ah[aoff]);
            short8 al = *reinterpret_cast<const short8*>(&Al[aoff]);
#pragma unroll
            for (int cg = 0; cg < CGS; ++cg) {
                const int coll = wc * (BN / 2) + cg * 32 + r31;
                const int boff = coll * 32 + ((kb ^ (r31 & 3)) << 3);
                short8 bh = *reinterpret_cast<const short8*>(&Bh[boff]);
                short8 bl = *reinterpret_cast<const short8*>(&Bl[boff]);
                acc[cg] = __builtin_amdgcn_mfma_f32_32x32x16_bf16(ah, bh, acc[cg], 0, 0, 0);
                acc[cg] = __builtin_amdgcn_mfma_f32_32x32x16_bf16(ah, bl, acc[cg], 0, 0, 0);
                acc[cg] = __builtin_amdgcn_mfma_f32_32x32x16_bf16(al, bh, acc[cg], 0, 0, 0);
            }
            if (alpha_wave) {
                short8 vh = {}, vl = {};
                if (r31 < 8) {
                    vh = *reinterpret_cast<const short8*>(&Vh[r31 * 32 + (kb << 3)]);
                    vl = *reinterpret_cast<const short8*>(&Vl[r31 * 32 + (kb << 3)]);
                }
                accv = __builtin_amdgcn_mfma_f32_32x32x16_bf16(ah, vh, accv, 0, 0, 0);
                accv = __builtin_amdgcn_mfma_f32_32x32x16_bf16(ah, vl, accv, 0, 0, 0);
                accv = __builtin_amdgcn_mfma_f32_32x32x16_bf16(al, vh, accv, 0, 0, 0);
            }
        }
    }

#pragma unroll
    for (int cg = 0; cg < CGS; ++cg) {
#pragma unroll
        for (int reg = 0; reg < 16; ++reg) {
            const int row = row0 + wr * 32 + (reg & 3) + 8 * (reg >> 2) + 4 * khw;
            if (row < nrows) {
                const int col = c0 + wc * (BN / 2) + cg * 32 + r31;
                H16[(size_t)row * OUTC + col] = (_Float16)acc[cg][reg];
            }
        }
    }
    if (alpha_wave && r31 < 8) {
        const int hsel = r31 & 3;
        if (hsel < HA) {
            float* dstp = (r31 < 4) ? alpha_s : alpha_d;
#pragma unroll
            for (int reg = 0; reg < 16; ++reg) {
                const int row = row0 + wr * 32 + (reg & 3) + 8 * (reg >> 2) + 4 * khw;
                if (row < nrows) dstp[(size_t)row * HA + hsel] = accv[reg];
            }
        }
    }
}

// ---------------- fused segment-softmax + aggregation, 4 heads ----------------
// One wave per node. Fast path (deg<=64): src idx + ex weights stay on-chip
// (regs + per-wave LDS slice); phase 2 = pure h16 gathers, 4-edge unroll.
template <bool RELU>
__global__ __launch_bounds__(256) void maxagg4_kernel(const _Float16* __restrict__ h,
                                                      const float* __restrict__ alpha_s,
                                                      const float* __restrict__ alpha_d,
                                                      const int* __restrict__ offs,
                                                      const int* __restrict__ csr,
                                                      float* __restrict__ w,
                                                      const float* __restrict__ bias,
                                                      float* __restrict__ out, int n_nodes) {
    __shared__ float wsh[4][64 * 4];
    const int gw = (blockIdx.x * blockDim.x + threadIdx.x) >> 6;
    const int lane = threadIdx.x & 63;
    const int wid = (threadIdx.x >> 6) & 3;
    if (gw >= n_nodes) return;
    const int start = offs[gw];
    const int end = offs[gw + 1];
    const int deg = end - start;
    const float4 ad = *reinterpret_cast<const float4*>(&alpha_d[(size_t)gw * 4]);
    const int head = lane >> 4;
    const int cb = lane << 2;
    float4 r;
    float4 acc = make_float4(0.f, 0.f, 0.f, 0.f);

    if (deg <= 64) {
        // ---- phase 1: one edge per lane, all on-chip ----
        const int i = start + lane;
        const bool has = i < end;
        int s_reg = 0;
        float4 e = make_float4(0.f, 0.f, 0.f, 0.f);
        float4 m = make_float4(-INFINITY, -INFINITY, -INFINITY, -INFINITY);
        if (has) {
            s_reg = csr[i];
            const float4 a = *reinterpret_cast<const float4*>(&alpha_s[(size_t)s_reg * 4]);
            e.x = leaky(a.x + ad.x);
            e.y = leaky(a.y + ad.y);
            e.z = leaky(a.z + ad.z);
            e.w = leaky(a.w + ad.w);
            m = e;
        }
#pragma unroll
        for (int o = 32; o; o >>= 1) {
            m.x = fmaxf(m.x, __shfl_xor(m.x, o));
            m.y = fmaxf(m.y, __shfl_xor(m.y, o));
            m.z = fmaxf(m.z, __shfl_xor(m.z, o));
            m.w = fmaxf(m.w, __shfl_xor(m.w, o));
        }
        float4 ex = make_float4(0.f, 0.f, 0.f, 0.f);
        if (has) {
            ex.x = __expf(e.x - m.x);
            ex.y = __expf(e.y - m.y);
            ex.z = __expf(e.z - m.z);
            ex.w = __expf(e.w - m.w);
        }
        float4 sum = ex;
#pragma unroll
        for (int o = 32; o; o >>= 1) {
            sum.x += __shfl_xor(sum.x, o);
            sum.y += __shfl_xor(sum.y, o);
            sum.z += __shfl_xor(sum.z, o);
            sum.w += __shfl_xor(sum.w, o);
        }
        r.x = 1.f / (sum.x + 1e-16f);
        r.y = 1.f / (sum.y + 1e-16f);
        r.z = 1.f / (sum.z + 1e-16f);
        r.w = 1.f / (sum.w + 1e-16f);
        // weights to per-wave LDS slice (zero-padded) — wave-local, no barrier
        *reinterpret_cast<float4*>(&wsh[wid][lane * 4]) = ex;
        // ---- phase 2: 4-edge unroll, shfl-broadcast src, LDS-broadcast weight ----
        const int degr = (deg + 3) & ~3;
        const float* wrow = wsh[wid];
        for (int j = 0; j < degr; j += 4) {
#pragma unroll
            for (int u = 0; u < 4; ++u) {
                const int s = __shfl(s_reg, j + u);
                const float wv = wrow[(j + u) * 4 + head];
                const uint2 uv = *reinterpret_cast<const uint2*>(&h[(size_t)s * 256 + cb]);
                const float2 f0 = __half22float2(__builtin_bit_cast(__half2, uv.x));
                const float2 f1 = __half22float2(__builtin_bit_cast(__half2, uv.y));
                acc.x = fmaf(wv, f0.x, acc.x);
                acc.y = fmaf(wv, f0.y, acc.y);
                acc.z = fmaf(wv, f1.x, acc.z);
                acc.w = fmaf(wv, f1.y, acc.w);
            }
        }
    } else {
        // ---- slow path (deg > 64): two-phase via global w ----
        float4 m = make_float4(-INFINITY, -INFINITY, -INFINITY, -INFINITY);
        float4 sum = make_float4(0.f, 0.f, 0.f, 0.f);
        for (int i = start + lane; i < end; i += 64) {
            const int s = csr[i];
            const float4 a = *reinterpret_cast<const float4*>(&alpha_s[(size_t)s * 4]);
            float4 e;
            e.x = leaky(a.x + ad.x);
            e.y = leaky(a.y + ad.y);
            e.z = leaky(a.z + ad.z);
            e.w = leaky(a.w + ad.w);
            *reinterpret_cast<float4*>(&w[(size_t)i * 4]) = e;
            m.x = fmaxf(m.x, e.x);
            m.y = fmaxf(m.y, e.y);
            m.z = fmaxf(m.z, e.z);
            m.w = fmaxf(m.w, e.w);
        }
#pragma unroll
        for (int o = 32; o; o >>= 1) {
            m.x = fmaxf(m.x, __shfl_xor(m.x, o));
            m.y = fmaxf(m.y, __shfl_xor(m.y, o));
            m.z = fmaxf(m.z, __shfl_xor(m.z, o));
            m.w = fmaxf(m.w, __shfl_xor(m.w, o));
        }
        for (int i = start + lane; i < end; i += 64) {
            float4 e = *reinterpret_cast<float4*>(&w[(size_t)i * 4]);
            e.x = __expf(e.x - m.x);
            e.y = __expf(e.y - m.y);
            e.z = __expf(e.z - m.z);
            e.w = __expf(e.w - m.w);
            *reinterpret_cast<float4*>(&w[(size_t)i * 4]) = e;
            sum.x += e.x;
            sum.y += e.y;
            sum.z += e.z;
            sum.w += e.w;
        }
#pragma unroll
        for (int o = 32; o; o >>= 1) {
            sum.x += __shfl_xor(sum.x, o);
            sum.y += __shfl_xor(sum.y, o);
            sum.z += __shfl_xor(sum.z, o);
            sum.w += __shfl_xor(sum.w, o);
        }
        r.x = 1.f / (sum.x + 1e-16f);
        r.y = 1.f / (sum.y + 1e-16f);
        r.z = 1.f / (sum.z + 1e-16f);
        r.w = 1.f / (sum.w + 1e-16f);
        for (int i = start; i < end; ++i) {
            const int s = csr[i];
            const float4 w0 = *reinterpret_cast<const float4*>(&w[(size_t)i * 4]);
            const float wv = head == 0 ? w0.x : head == 1 ? w0.y : head == 2 ? w0.z : w0.w;
            const uint2 uv = *reinterpret_cast<const uint2*>(&h[(size_t)s * 256 + cb]);
            const float2 f0 = __half22float2(__builtin_bit_cast(__half2, uv.x));
            const float2 f1 = __half22float2(__builtin_bit_cast(__half2, uv.y));
            acc.x = fmaf(wv, f0.x, acc.x);
            acc.y = fmaf(wv, f0.y, acc.y);
            acc.z = fmaf(wv, f1.x, acc.z);
            acc.w = fmaf(wv, f1.y, acc.w);
        }
    }

    const float rv = head == 0 ? r.x : head == 1 ? r.y : head == 2 ? r.z : r.w;
    const float4 b4 = *reinterpret_cast<const float4*>(&bias[cb]);
    float4 o;
    o.x = acc.x * rv + b4.x;
    o.y = acc.y * rv + b4.y;
    o.z = acc.z * rv + b4.z;
    o.w = acc.w * rv + b4.w;
    if (RELU) {
        o.x = fmaxf(o.x, 0.f);
        o.y = fmaxf(o.y, 0.f);
        o.z = fmaxf(o.z, 0.f);
        o.w = fmaxf(o.w, 0.f);
    }
    *reinterpret_cast<float4*>(&out[(size_t)gw * 256 + cb]) = o;
}

// ---------------- fused softmax + aggregation, 1 head ----------------
template <bool RELU>
__global__ __launch_bounds__(256) void maxagg1_kernel(const _Float16* __restrict__ h,
                                                      const float* __restrict__ alpha_s,
                                                      const float* __restrict__ alpha_d,
                                                      const int* __restrict__ offs,
                                                      const int* __restrict__ csr,
                                                      float* __restrict__ w,
                                                      const float* __restrict__ bias,
                                                      float* __restrict__ out, int n_nodes) {
    const int gw = (blockIdx.x * blockDim.x + threadIdx.x) >> 6;
    const int lane = threadIdx.x & 63;
    if (gw >= n_nodes) return;
    const int start = offs[gw];
    const int end = offs[gw + 1];
    const int deg = end - start;
    const float ad = alpha_d[gw];
    float r;
    float acc = 0.f;

    if (deg <= 64) {
        const int i = start + lane;
        const bool has = i < end;
        int s_reg = 0;
        float e = 0.f, m = -INFINITY;
        if (has) {
            s_reg = csr[i];
            e = leaky(alpha_s[s_reg] + ad);
            m = e;
        }
#pragma unroll
        for (int o = 32; o; o >>= 1) m = fmaxf(m, __shfl_xor(m, o));
        float ex = has ? __expf(e - m) : 0.f;
        float sum = ex;
#pragma unroll
        for (int o = 32; o; o >>= 1) sum += __shfl_xor(sum, o);
        r = 1.f / (sum + 1e-16f);
        const int degr = (deg + 3) & ~3;
        for (int j = 0; j < degr; j += 4) {
#pragma unroll
            for (int u = 0; u < 4; ++u) {
                const int s = __shfl(s_reg, j + u);
                const float wv = __shfl(ex, j + u);
                acc = fmaf(wv, (float)h[(size_t)s * 64 + lane], acc);
            }
        }
    } else {
        float m = -INFINITY, sum = 0.f;
        for (int i = start + lane; i < end; i += 64) {
            const float e = leaky(alpha_s[csr[i]] + ad);
            w[i] = e;
            m = fmaxf(m, e);
        }
#pragma unroll
        for (int o = 32; o; o >>= 1) m = fmaxf(m, __shfl_xor(m, o));
        for (int i = start + lane; i < end; i += 64) {
            const float ex = __expf(w[i] - m);
            w[i] = ex;
            sum += ex;
        }
#pragma unroll
        for (int o = 32; o; o >>= 1) sum += __shfl_xor(sum, o);
        r = 1.f / (sum + 1e-16f);
        for (int i = start; i < end; ++i)
            acc = fmaf(w[i], (float)h[(size_t)csr[i] * 64 + lane], acc);
    }
    float o = acc * r + bias[lane];
    if (RELU) o = fmaxf(o, 0.f);
    out[(size_t)gw * 64 + lane] = o;
}

// ---------------- launch ----------------
extern "C" void kernel_launch(void* const* d_in, const int* in_sizes, int n_in,
                              void* d_out, int out_size, void* d_ws, size_t ws_size,
                              hipStream_t stream) {
    const float* x   = (const float*)d_in[0];
    const int*   ei  = (const int*)d_in[1];
    const float* W1  = (const float*)d_in[2];
    const float* a1s = (const float*)d_in[3];
    const float* a1d = (const float*)d_in[4];
    const float* b1  = (const float*)d_in[5];
    const float* W2  = (const float*)d_in[6];
    const float* a2s = (const float*)d_in[7];
    const float* a2d = (const float*)d_in[8];
    const float* b2  = (const float*)d_in[9];
    const float* W3  = (const float*)d_in[10];
    const float* a3s = (const float*)d_in[11];
    const float* a3d = (const float*)d_in[12];
    const float* b3  = (const float*)d_in[13];
    float* out = (float*)d_out;

    const int N = in_sizes[0] / HID;
    const int E = in_sizes[1] / 2;
    const int* src = ei;
    const int* dst = ei + E;

    char* p = (char*)d_ws;
    auto alloc = [&](size_t bytes) {
        char* q = p;
        p += (bytes + 255) & ~(size_t)255;
        return q;
    };
    float* bufA = (float*)alloc((size_t)N * 256 * 4);
    float* bufB = (float*)alloc((size_t)N * 256 * 4);
    _Float16* h16 = (_Float16*)alloc((size_t)N * 256 * 2);
    float* alpS = (float*)alloc((size_t)N * NHEADS * 4);
    float* alpD = (float*)alloc((size_t)N * NHEADS * 4);
    float* wbuf = (float*)alloc((size_t)E * NHEADS * 4);
    int* counts = (int*)alloc((size_t)N * 4);
    int* offs   = (int*)alloc((size_t)(N + 1) * 4);
    int* wp     = (int*)alloc((size_t)N * 4);
    int* csr    = (int*)alloc((size_t)E * 4);
    int* bsum   = (int*)alloc((size_t)256 * 4);
    us* wt1h = (us*)alloc((size_t)64 * 256 * 2);
    us* wt1l = (us*)alloc((size_t)64 * 256 * 2);
    us* wt2h = (us*)alloc((size_t)256 * 256 * 2);
    us* wt2l = (us*)alloc((size_t)256 * 256 * 2);
    us* wt3h = (us*)alloc((size_t)256 * 64 * 2);
    us* wt3l = (us*)alloc((size_t)256 * 64 * 2);
    us* va1h = (us*)alloc((size_t)8 * 64 * 2);
    us* va1l = (us*)alloc((size_t)8 * 64 * 2);
    us* va2h = (us*)alloc((size_t)8 * 256 * 2);
    us* va2l = (us*)alloc((size_t)8 * 256 * 2);
    us* va3h = (us*)alloc((size_t)8 * 256 * 2);
    us* va3l = (us*)alloc((size_t)8 * 256 * 2);

    hipMemsetAsync(counts, 0, (size_t)N * 4, stream);
    const int eb = (E + 255) / 256;
    const int nb = (N + 255) / 256;
    histo_kernel<<<eb, 256, 0, stream>>>(dst, counts, E);
    scanA_kernel<<<nb, 256, 0, stream>>>(counts, bsum, N);
    scanB_kernel<<<1, 256, 0, stream>>>(bsum, nb);
    scanC_kernel<<<nb, 256, 0, stream>>>(counts, bsum, offs, wp, N);
    scatter_kernel<<<eb, 256, 0, stream>>>(src, dst, wp, csr, E);

    prep_kernel<<<(102912 + 255) / 256, 256, 0, stream>>>(
        W1, W2, W3, a1s, a1d, a2s, a2d, a3s, a3d,
        wt1h, wt1l, wt2h, wt2l, wt3h, wt3l,
        va1h, va1l, va2h, va2l, va3h, va3l);

    const int gb64 = (N + 63) / 64;
    const int nwb = (N * 64 + 255) / 256;

    // layer 1
    gemm_mfma_kernel<64, 256, 128, 4><<<dim3(gb64, 2), 256, 0, stream>>>(
        x, wt1h, wt1l, va1h, va1l, h16, alpS, alpD, N);
    maxagg4_kernel<true><<<nwb, 256, 0, stream>>>(h16, alpS, alpD, offs, csr, wbuf, b1, bufB, N);

    // layer 2
    gemm_mfma_kernel<256, 256, 128, 4><<<dim3(gb64, 2), 256, 0, stream>>>(
        bufB, wt2h, wt2l, va2h, va2l, h16, alpS, alpD, N);
    maxagg4_kernel<true><<<nwb, 256, 0, stream>>>(h16, alpS, alpD, offs, csr, wbuf, b2, bufA, N);

    // layer 3
    gemm_mfma_kernel<256, 64, 64, 1><<<dim3(gb64, 1), 256, 0, stream>>>(
        bufA, wt3h, wt3l, va3h, va3l, h16, alpS, alpD, N);
    maxagg1_kernel<false><<<nwb, 256, 0, stream>>>(h16, alpS, alpD, offs, csr, wbuf, b3, out, N);
}

// Round 11
// 167.460 us; speedup vs baseline: 2.5666x; 1.0250x over previous
//
#include <hip/hip_runtime.h>
#include <hip/hip_bf16.h>
#include <hip/hip_fp16.h>
#include <cstdint>

#define HID 64
#define NHEADS 4
#define NEG_SLOPE 0.2f

typedef __attribute__((ext_vector_type(8))) short short8;
typedef __attribute__((ext_vector_type(16))) float f32x16;
typedef unsigned short us;

__device__ __forceinline__ us f2bf(float f) {
    unsigned int u = __float_as_uint(f);
    unsigned int r = (u + 0x7FFFu + ((u >> 16) & 1u)) >> 16;
    return (us)r;
}
__device__ __forceinline__ float bf2f(us h) {
    return __uint_as_float(((unsigned int)h) << 16);
}
__device__ __forceinline__ float leaky(float e) {
    return (e > 0.f) ? e : NEG_SLOPE * e;
}

// ---------------- CSR build ----------------
__global__ void histo_kernel(const int* __restrict__ dst, int* __restrict__ counts, int E) {
    int i = blockIdx.x * blockDim.x + threadIdx.x;
    if (i < E) atomicAdd(&counts[dst[i]], 1);
}

__global__ __launch_bounds__(256) void scanA_kernel(const int* __restrict__ counts,
                                                    int* __restrict__ bsum, int n) {
    const int i = blockIdx.x * 256 + threadIdx.x;
    int v = (i < n) ? counts[i] : 0;
#pragma unroll
    for (int o = 32; o; o >>= 1) v += __shfl_xor(v, o);
    __shared__ int ws[4];
    if ((threadIdx.x & 63) == 0) ws[threadIdx.x >> 6] = v;
    __syncthreads();
    if (threadIdx.x == 0) bsum[blockIdx.x] = ws[0] + ws[1] + ws[2] + ws[3];
}

__global__ __launch_bounds__(256) void scanB_kernel(int* __restrict__ bsum, int nb) {
    __shared__ int sh[256];
    const int t = threadIdx.x;
    const int v = (t < nb) ? bsum[t] : 0;
    sh[t] = v;
    __syncthreads();
    for (int o = 1; o < 256; o <<= 1) {
        int u = (t >= o) ? sh[t - o] : 0;
        __syncthreads();
        sh[t] += u;
        __syncthreads();
    }
    if (t < nb) bsum[t] = sh[t] - v;
}

__global__ __launch_bounds__(256) void scanC_kernel(const int* __restrict__ counts,
                                                    const int* __restrict__ bsum,
                                                    int* __restrict__ offs,
                                                    int* __restrict__ wp, int n) {
    __shared__ int sh[256];
    const int t = threadIdx.x;
    const int i = blockIdx.x * 256 + t;
    const int v = (i < n) ? counts[i] : 0;
    sh[t] = v;
    __syncthreads();
    for (int o = 1; o < 256; o <<= 1) {
        int u = (t >= o) ? sh[t - o] : 0;
        __syncthreads();
        sh[t] += u;
        __syncthreads();
    }
    const int base = bsum[blockIdx.x];
    if (i < n) {
        const int off = base + sh[t] - v;
        offs[i] = off;
        wp[i] = off;
        if (i == n - 1) offs[n] = base + sh[t];
    }
}

__global__ void scatter_kernel(const int* __restrict__ src, const int* __restrict__ dst,
                               int* __restrict__ wp, int* __restrict__ csr, int E) {
    int i = blockIdx.x * blockDim.x + threadIdx.x;
    if (i < E) {
        int d = dst[i];
        int p = atomicAdd(&wp[d], 1);
        csr[p] = src[i];
    }
}

// ---------------- prep: W split (3x) + va = W@a precompute (3x) ----------------
__device__ __forceinline__ void wsplit_one(const float* __restrict__ W, us* __restrict__ WTh,
                                           us* __restrict__ WTl, int K, int OUTC, int i) {
    const int c = i / K;
    const int k = i - c * K;
    const float v = W[(size_t)k * OUTC + c];
    const us h = f2bf(v);
    WTh[i] = h;
    WTl[i] = f2bf(v - bf2f(h));
}

__device__ __forceinline__ void vaprep_one(const float* __restrict__ W,
                                           const float* __restrict__ as,
                                           const float* __restrict__ ad,
                                           us* __restrict__ vh, us* __restrict__ vl,
                                           int K, int OUTC, int H, int i) {
    const int j = i / K;
    const int k = i - j * K;
    const int hh = (j < 4) ? j : j - 4;
    const float* a = (j < 4) ? as : ad;
    float acc = 0.f;
    if (hh < H) {
        for (int c = 0; c < 64; ++c)
            acc += W[(size_t)k * OUTC + hh * 64 + c] * a[hh * 64 + c];
    }
    const us h = f2bf(acc);
    vh[i] = h;
    vl[i] = f2bf(acc - bf2f(h));
}

__global__ __launch_bounds__(256) void prep_kernel(
    const float* W1, const float* W2, const float* W3,
    const float* a1s, const float* a1d, const float* a2s, const float* a2d,
    const float* a3s, const float* a3d,
    us* wt1h, us* wt1l, us* wt2h, us* wt2l, us* wt3h, us* wt3l,
    us* va1h, us* va1l, us* va2h, us* va2l, us* va3h, us* va3l) {
    int idx = blockIdx.x * 256 + threadIdx.x;
    if (idx < 16384) { wsplit_one(W1, wt1h, wt1l, 64, 256, idx); return; }
    idx -= 16384;
    if (idx < 65536) { wsplit_one(W2, wt2h, wt2l, 256, 256, idx); return; }
    idx -= 65536;
    if (idx < 16384) { wsplit_one(W3, wt3h, wt3l, 256, 64, idx); return; }
    idx -= 16384;
    if (idx < 512) { vaprep_one(W1, a1s, a1d, va1h, va1l, 64, 256, 4, idx); return; }
    idx -= 512;
    if (idx < 2048) { vaprep_one(W2, a2s, a2d, va2h, va2l, 256, 256, 4, idx); return; }
    idx -= 2048;
    if (idx < 2048) { vaprep_one(W3, a3s, a3d, va3h, va3l, 256, 64, 1, idx); return; }
}

// ---------------- GEMM via MFMA split-bf16 + fused MFMA alpha ----------------
template <int K, int OUTC, int BN, int HA>
__global__ __launch_bounds__(256) void gemm_mfma_kernel(const float* __restrict__ X,
                                                        const us* __restrict__ WTh,
                                                        const us* __restrict__ WTl,
                                                        const us* __restrict__ vah,
                                                        const us* __restrict__ val,
                                                        _Float16* __restrict__ H16,
                                                        float* __restrict__ alpha_s,
                                                        float* __restrict__ alpha_d, int nrows) {
    constexpr int CGS = BN / 64;
    constexpr int NB = BN / 64;
    constexpr int TPC = 4 / NB;
    __shared__ short Ah[64 * 32];
    __shared__ short Al[64 * 32];
    __shared__ short Bh[BN * 32];
    __shared__ short Bl[BN * 32];
    __shared__ short Vh[8 * 32];
    __shared__ short Vl[8 * 32];

    const int tid = threadIdx.x;
    const int lane = tid & 63;
    const int wid = tid >> 6;
    const int wr = wid >> 1;
    const int wc = wid & 1;
    const int r31 = lane & 31;
    const int khw = lane >> 5;
    const int row0 = blockIdx.x * 64;
    const int c0 = blockIdx.y * BN;
    const bool alpha_blk = (blockIdx.y == 0);
    const bool alpha_wave = alpha_blk && (wc == 0);

    const int ar = tid >> 2;
    const int akq = (tid & 3) * 8;
    const int arow = row0 + ar;
    const bool aok = arow < nrows;

    const int bcol = tid / TPC;
    const int bkb = (tid % TPC) * NB;

    f32x16 acc[CGS];
#pragma unroll
    for (int cg = 0; cg < CGS; ++cg)
#pragma unroll
        for (int r = 0; r < 16; ++r) acc[cg][r] = 0.f;
    f32x16 accv;
#pragma unroll
    for (int r = 0; r < 16; ++r) accv[r] = 0.f;

    for (int k0 = 0; k0 < K; k0 += 32) {
        __syncthreads();
        {
            float4 v0 = make_float4(0.f, 0.f, 0.f, 0.f), v1 = v0;
            if (aok) {
                v0 = *reinterpret_cast<const float4*>(&X[(size_t)arow * K + k0 + akq]);
                v1 = *reinterpret_cast<const float4*>(&X[(size_t)arow * K + k0 + akq + 4]);
            }
            float vs[8] = {v0.x, v0.y, v0.z, v0.w, v1.x, v1.y, v1.z, v1.w};
            short8 hi, lo;
#pragma unroll
            for (int j = 0; j < 8; ++j) {
                us h = f2bf(vs[j]);
                hi[j] = (short)h;
                lo[j] = (short)f2bf(vs[j] - bf2f(h));
            }
            const int blk = (akq >> 3) ^ (ar & 3);
            const int off = ar * 32 + (blk << 3);
            *reinterpret_cast<short8*>(&Ah[off]) = hi;
            *reinterpret_cast<short8*>(&Al[off]) = lo;
        }
        {
            const us* srcH = &WTh[(size_t)(c0 + bcol) * K + k0 + bkb * 8];
            const us* srcL = &WTl[(size_t)(c0 + bcol) * K + k0 + bkb * 8];
#pragma unroll
            for (int b = 0; b < NB; ++b) {
                short8 h = *reinterpret_cast<const short8*>(&srcH[b * 8]);
                short8 l = *reinterpret_cast<const short8*>(&srcL[b * 8]);
                const int blk = (bkb + b) ^ (bcol & 3);
                const int off = bcol * 32 + (blk << 3);
                *reinterpret_cast<short8*>(&Bh[off]) = h;
                *reinterpret_cast<short8*>(&Bl[off]) = l;
            }
        }
        if (alpha_blk && tid < 32) {
            const int col = tid >> 2, kb2 = tid & 3;
            *reinterpret_cast<short8*>(&Vh[col * 32 + kb2 * 8]) =
                *reinterpret_cast<const short8*>(&vah[col * K + k0 + kb2 * 8]);
            *reinterpret_cast<short8*>(&Vl[col * 32 + kb2 * 8]) =
                *reinterpret_cast<const short8*>(&val[col * K + k0 + kb2 * 8]);
        }
        __syncthreads();
#pragma unroll
        for (int ks = 0; ks < 32; ks += 16) {
            const int kb = (ks >> 3) + khw;
            const int aoff = (wr * 32 + r31) * 32 + ((kb ^ (r31 & 3)) << 3);
            short8 ah = *reinterpret_cast<const short8*>(&Ah[aoff]);
            short8 al = *reinterpret_cast<const short8*>(&Al[aoff]);
#pragma unroll
            for (int cg = 0; cg < CGS; ++cg) {
                const int coll = wc * (BN / 2) + cg * 32 + r31;
                const int boff = coll * 32 + ((kb ^ (r31 & 3)) << 3);
                short8 bh = *reinterpret_cast<const short8*>(&Bh[boff]);
                short8 bl = *reinterpret_cast<const short8*>(&Bl[boff]);
                acc[cg] = __builtin_amdgcn_mfma_f32_32x32x16_bf16(ah, bh, acc[cg], 0, 0, 0);
                acc[cg] = __builtin_amdgcn_mfma_f32_32x32x16_bf16(ah, bl, acc[cg], 0, 0, 0);
                acc[cg] = __builtin_amdgcn_mfma_f32_32x32x16_bf16(al, bh, acc[cg], 0, 0, 0);
            }
            if (alpha_wave) {
                short8 vh = {}, vl = {};
                if (r31 < 8) {
                    vh = *reinterpret_cast<const short8*>(&Vh[r31 * 32 + (kb << 3)]);
                    vl = *reinterpret_cast<const short8*>(&Vl[r31 * 32 + (kb << 3)]);
                }
                accv = __builtin_amdgcn_mfma_f32_32x32x16_bf16(ah, vh, accv, 0, 0, 0);
                accv = __builtin_amdgcn_mfma_f32_32x32x16_bf16(ah, vl, accv, 0, 0, 0);
                accv = __builtin_amdgcn_mfma_f32_32x32x16_bf16(al, vh, accv, 0, 0, 0);
            }
        }
    }

#pragma unroll
    for (int cg = 0; cg < CGS; ++cg) {
#pragma unroll
        for (int reg = 0; reg < 16; ++reg) {
            const int row = row0 + wr * 32 + (reg & 3) + 8 * (reg >> 2) + 4 * khw;
            if (row < nrows) {
                const int col = c0 + wc * (BN / 2) + cg * 32 + r31;
                H16[(size_t)row * OUTC + col] = (_Float16)acc[cg][reg];
            }
        }
    }
    if (alpha_wave && r31 < 8) {
        const int hsel = r31 & 3;
        if (hsel < HA) {
            float* dstp = (r31 < 4) ? alpha_s : alpha_d;
#pragma unroll
            for (int reg = 0; reg < 16; ++reg) {
                const int row = row0 + wr * 32 + (reg & 3) + 8 * (reg >> 2) + 4 * khw;
                if (row < nrows) dstp[(size_t)row * HA + hsel] = accv[reg];
            }
        }
    }
}

// ---------------- fused segment-softmax + aggregation, 4 heads ----------------
// One wave per block per node. Fast path (deg<=64): src idx + ex weights on-chip;
// phase 2 = pure h16 gathers, 8-edge unroll (8 in flight).
template <bool RELU>
__global__ __launch_bounds__(64) void maxagg4_kernel(const _Float16* __restrict__ h,
                                                     const float* __restrict__ alpha_s,
                                                     const float* __restrict__ alpha_d,
                                                     const int* __restrict__ offs,
                                                     const int* __restrict__ csr,
                                                     float* __restrict__ w,
                                                     const float* __restrict__ bias,
                                                     float* __restrict__ out, int n_nodes) {
    __shared__ float wsh[64 * 4];
    const int gw = blockIdx.x;
    const int lane = threadIdx.x;
    if (gw >= n_nodes) return;
    const int start = offs[gw];
    const int end = offs[gw + 1];
    const int deg = end - start;
    const float4 ad = *reinterpret_cast<const float4*>(&alpha_d[(size_t)gw * 4]);
    const int head = lane >> 4;
    const int cb = lane << 2;
    float4 r;
    float4 acc = make_float4(0.f, 0.f, 0.f, 0.f);

    if (deg <= 64) {
        const int i = start + lane;
        const bool has = i < end;
        int s_reg = 0;
        float4 e = make_float4(0.f, 0.f, 0.f, 0.f);
        float4 m = make_float4(-INFINITY, -INFINITY, -INFINITY, -INFINITY);
        if (has) {
            s_reg = csr[i];
            const float4 a = *reinterpret_cast<const float4*>(&alpha_s[(size_t)s_reg * 4]);
            e.x = leaky(a.x + ad.x);
            e.y = leaky(a.y + ad.y);
            e.z = leaky(a.z + ad.z);
            e.w = leaky(a.w + ad.w);
            m = e;
        }
#pragma unroll
        for (int o = 32; o; o >>= 1) {
            m.x = fmaxf(m.x, __shfl_xor(m.x, o));
            m.y = fmaxf(m.y, __shfl_xor(m.y, o));
            m.z = fmaxf(m.z, __shfl_xor(m.z, o));
            m.w = fmaxf(m.w, __shfl_xor(m.w, o));
        }
        float4 ex = make_float4(0.f, 0.f, 0.f, 0.f);
        if (has) {
            ex.x = __expf(e.x - m.x);
            ex.y = __expf(e.y - m.y);
            ex.z = __expf(e.z - m.z);
            ex.w = __expf(e.w - m.w);
        }
        float4 sum = ex;
#pragma unroll
        for (int o = 32; o; o >>= 1) {
            sum.x += __shfl_xor(sum.x, o);
            sum.y += __shfl_xor(sum.y, o);
            sum.z += __shfl_xor(sum.z, o);
            sum.w += __shfl_xor(sum.w, o);
        }
        r.x = 1.f / (sum.x + 1e-16f);
        r.y = 1.f / (sum.y + 1e-16f);
        r.z = 1.f / (sum.z + 1e-16f);
        r.w = 1.f / (sum.w + 1e-16f);
        *reinterpret_cast<float4*>(&wsh[lane * 4]) = ex;  // zero-padded, wave-local
        const int degr = (deg + 7) & ~7;
        for (int j = 0; j < degr; j += 8) {
#pragma unroll
            for (int u = 0; u < 8; ++u) {
                const int s = __shfl(s_reg, j + u);
                const float wv = wsh[(j + u) * 4 + head];
                const uint2 uv = *reinterpret_cast<const uint2*>(&h[(size_t)s * 256 + cb]);
                const float2 f0 = __half22float2(__builtin_bit_cast(__half2, uv.x));
                const float2 f1 = __half22float2(__builtin_bit_cast(__half2, uv.y));
                acc.x = fmaf(wv, f0.x, acc.x);
                acc.y = fmaf(wv, f0.y, acc.y);
                acc.z = fmaf(wv, f1.x, acc.z);
                acc.w = fmaf(wv, f1.y, acc.w);
            }
        }
    } else {
        float4 m = make_float4(-INFINITY, -INFINITY, -INFINITY, -INFINITY);
        float4 sum = make_float4(0.f, 0.f, 0.f, 0.f);
        for (int i = start + lane; i < end; i += 64) {
            const int s = csr[i];
            const float4 a = *reinterpret_cast<const float4*>(&alpha_s[(size_t)s * 4]);
            float4 e;
            e.x = leaky(a.x + ad.x);
            e.y = leaky(a.y + ad.y);
            e.z = leaky(a.z + ad.z);
            e.w = leaky(a.w + ad.w);
            *reinterpret_cast<float4*>(&w[(size_t)i * 4]) = e;
            m.x = fmaxf(m.x, e.x);
            m.y = fmaxf(m.y, e.y);
            m.z = fmaxf(m.z, e.z);
            m.w = fmaxf(m.w, e.w);
        }
#pragma unroll
        for (int o = 32; o; o >>= 1) {
            m.x = fmaxf(m.x, __shfl_xor(m.x, o));
            m.y = fmaxf(m.y, __shfl_xor(m.y, o));
            m.z = fmaxf(m.z, __shfl_xor(m.z, o));
            m.w = fmaxf(m.w, __shfl_xor(m.w, o));
        }
        for (int i = start + lane; i < end; i += 64) {
            float4 e = *reinterpret_cast<float4*>(&w[(size_t)i * 4]);
            e.x = __expf(e.x - m.x);
            e.y = __expf(e.y - m.y);
            e.z = __expf(e.z - m.z);
            e.w = __expf(e.w - m.w);
            *reinterpret_cast<float4*>(&w[(size_t)i * 4]) = e;
            sum.x += e.x;
            sum.y += e.y;
            sum.z += e.z;
            sum.w += e.w;
        }
#pragma unroll
        for (int o = 32; o; o >>= 1) {
            sum.x += __shfl_xor(sum.x, o);
            sum.y += __shfl_xor(sum.y, o);
            sum.z += __shfl_xor(sum.z, o);
            sum.w += __shfl_xor(sum.w, o);
        }
        r.x = 1.f / (sum.x + 1e-16f);
        r.y = 1.f / (sum.y + 1e-16f);
        r.z = 1.f / (sum.z + 1e-16f);
        r.w = 1.f / (sum.w + 1e-16f);
        for (int i = start; i < end; ++i) {
            const int s = csr[i];
            const float4 w0 = *reinterpret_cast<const float4*>(&w[(size_t)i * 4]);
            const float wv = head == 0 ? w0.x : head == 1 ? w0.y : head == 2 ? w0.z : w0.w;
            const uint2 uv = *reinterpret_cast<const uint2*>(&h[(size_t)s * 256 + cb]);
            const float2 f0 = __half22float2(__builtin_bit_cast(__half2, uv.x));
            const float2 f1 = __half22float2(__builtin_bit_cast(__half2, uv.y));
            acc.x = fmaf(wv, f0.x, acc.x);
            acc.y = fmaf(wv, f0.y, acc.y);
            acc.z = fmaf(wv, f1.x, acc.z);
            acc.w = fmaf(wv, f1.y, acc.w);
        }
    }

    const float rv = head == 0 ? r.x : head == 1 ? r.y : head == 2 ? r.z : r.w;
    const float4 b4 = *reinterpret_cast<const float4*>(&bias[cb]);
    float4 o;
    o.x = acc.x * rv + b4.x;
    o.y = acc.y * rv + b4.y;
    o.z = acc.z * rv + b4.z;
    o.w = acc.w * rv + b4.w;
    if (RELU) {
        o.x = fmaxf(o.x, 0.f);
        o.y = fmaxf(o.y, 0.f);
        o.z = fmaxf(o.z, 0.f);
        o.w = fmaxf(o.w, 0.f);
    }
    *reinterpret_cast<float4*>(&out[(size_t)gw * 256 + cb]) = o;
}

// ---------------- fused softmax + aggregation, 1 head ----------------
template <bool RELU>
__global__ __launch_bounds__(64) void maxagg1_kernel(const _Float16* __restrict__ h,
                                                     const float* __restrict__ alpha_s,
                                                     const float* __restrict__ alpha_d,
                                                     const int* __restrict__ offs,
                                                     const int* __restrict__ csr,
                                                     float* __restrict__ w,
                                                     const float* __restrict__ bias,
                                                     float* __restrict__ out, int n_nodes) {
    const int gw = blockIdx.x;
    const int lane = threadIdx.x;
    if (gw >= n_nodes) return;
    const int start = offs[gw];
    const int end = offs[gw + 1];
    const int deg = end - start;
    const float ad = alpha_d[gw];
    float r;
    float acc = 0.f;

    if (deg <= 64) {
        const int i = start + lane;
        const bool has = i < end;
        int s_reg = 0;
        float e = 0.f, m = -INFINITY;
        if (has) {
            s_reg = csr[i];
            e = leaky(alpha_s[s_reg] + ad);
            m = e;
        }
#pragma unroll
        for (int o = 32; o; o >>= 1) m = fmaxf(m, __shfl_xor(m, o));
        float ex = has ? __expf(e - m) : 0.f;
        float sum = ex;
#pragma unroll
        for (int o = 32; o; o >>= 1) sum += __shfl_xor(sum, o);
        r = 1.f / (sum + 1e-16f);
        const int degr = (deg + 7) & ~7;
        for (int j = 0; j < degr; j += 8) {
#pragma unroll
            for (int u = 0; u < 8; ++u) {
                const int s = __shfl(s_reg, j + u);
                const float wv = __shfl(ex, j + u);
                acc = fmaf(wv, (float)h[(size_t)s * 64 + lane], acc);
            }
        }
    } else {
        float m = -INFINITY, sum = 0.f;
        for (int i = start + lane; i < end; i += 64) {
            const float e = leaky(alpha_s[csr[i]] + ad);
            w[i] = e;
            m = fmaxf(m, e);
        }
#pragma unroll
        for (int o = 32; o; o >>= 1) m = fmaxf(m, __shfl_xor(m, o));
        for (int i = start + lane; i < end; i += 64) {
            const float ex = __expf(w[i] - m);
            w[i] = ex;
            sum += ex;
        }
#pragma unroll
        for (int o = 32; o; o >>= 1) sum += __shfl_xor(sum, o);
        r = 1.f / (sum + 1e-16f);
        for (int i = start; i < end; ++i)
            acc = fmaf(w[i], (float)h[(size_t)csr[i] * 64 + lane], acc);
    }
    float o = acc * r + bias[lane];
    if (RELU) o = fmaxf(o, 0.f);
    out[(size_t)gw * 64 + lane] = o;
}

// ---------------- launch ----------------
extern "C" void kernel_launch(void* const* d_in, const int* in_sizes, int n_in,
                              void* d_out, int out_size, void* d_ws, size_t ws_size,
                              hipStream_t stream) {
    const float* x   = (const float*)d_in[0];
    const int*   ei  = (const int*)d_in[1];
    const float* W1  = (const float*)d_in[2];
    const float* a1s = (const float*)d_in[3];
    const float* a1d = (const float*)d_in[4];
    const float* b1  = (const float*)d_in[5];
    const float* W2  = (const float*)d_in[6];
    const float* a2s = (const float*)d_in[7];
    const float* a2d = (const float*)d_in[8];
    const float* b2  = (const float*)d_in[9];
    const float* W3  = (const float*)d_in[10];
    const float* a3s = (const float*)d_in[11];
    const float* a3d = (const float*)d_in[12];
    const float* b3  = (const float*)d_in[13];
    float* out = (float*)d_out;

    const int N = in_sizes[0] / HID;
    const int E = in_sizes[1] / 2;
    const int* src = ei;
    const int* dst = ei + E;

    char* p = (char*)d_ws;
    auto alloc = [&](size_t bytes) {
        char* q = p;
        p += (bytes + 255) & ~(size_t)255;
        return q;
    };
    float* bufA = (float*)alloc((size_t)N * 256 * 4);
    float* bufB = (float*)alloc((size_t)N * 256 * 4);
    _Float16* h16 = (_Float16*)alloc((size_t)N * 256 * 2);
    float* alpS = (float*)alloc((size_t)N * NHEADS * 4);
    float* alpD = (float*)alloc((size_t)N * NHEADS * 4);
    float* wbuf = (float*)alloc((size_t)E * NHEADS * 4);
    int* counts = (int*)alloc((size_t)N * 4);
    int* offs   = (int*)alloc((size_t)(N + 1) * 4);
    int* wp     = (int*)alloc((size_t)N * 4);
    int* csr    = (int*)alloc((size_t)E * 4);
    int* bsum   = (int*)alloc((size_t)256 * 4);
    us* wt1h = (us*)alloc((size_t)64 * 256 * 2);
    us* wt1l = (us*)alloc((size_t)64 * 256 * 2);
    us* wt2h = (us*)alloc((size_t)256 * 256 * 2);
    us* wt2l = (us*)alloc((size_t)256 * 256 * 2);
    us* wt3h = (us*)alloc((size_t)256 * 64 * 2);
    us* wt3l = (us*)alloc((size_t)256 * 64 * 2);
    us* va1h = (us*)alloc((size_t)8 * 64 * 2);
    us* va1l = (us*)alloc((size_t)8 * 64 * 2);
    us* va2h = (us*)alloc((size_t)8 * 256 * 2);
    us* va2l = (us*)alloc((size_t)8 * 256 * 2);
    us* va3h = (us*)alloc((size_t)8 * 256 * 2);
    us* va3l = (us*)alloc((size_t)8 * 256 * 2);

    hipMemsetAsync(counts, 0, (size_t)N * 4, stream);
    const int eb = (E + 255) / 256;
    const int nb = (N + 255) / 256;
    histo_kernel<<<eb, 256, 0, stream>>>(dst, counts, E);
    scanA_kernel<<<nb, 256, 0, stream>>>(counts, bsum, N);
    scanB_kernel<<<1, 256, 0, stream>>>(bsum, nb);
    scanC_kernel<<<nb, 256, 0, stream>>>(counts, bsum, offs, wp, N);
    scatter_kernel<<<eb, 256, 0, stream>>>(src, dst, wp, csr, E);

    prep_kernel<<<(102912 + 255) / 256, 256, 0, stream>>>(
        W1, W2, W3, a1s, a1d, a2s, a2d, a3s, a3d,
        wt1h, wt1l, wt2h, wt2l, wt3h, wt3l,
        va1h, va1l, va2h, va2l, va3h, va3l);

    const int gb64 = (N + 63) / 64;

    // layer 1
    gemm_mfma_kernel<64, 256, 128, 4><<<dim3(gb64, 2), 256, 0, stream>>>(
        x, wt1h, wt1l, va1h, va1l, h16, alpS, alpD, N);
    maxagg4_kernel<true><<<N, 64, 0, stream>>>(h16, alpS, alpD, offs, csr, wbuf, b1, bufB, N);

    // layer 2
    gemm_mfma_kernel<256, 256, 128, 4><<<dim3(gb64, 2), 256, 0, stream>>>(
        bufB, wt2h, wt2l, va2h, va2l, h16, alpS, alpD, N);
    maxagg4_kernel<true><<<N, 64, 0, stream>>>(h16, alpS, alpD, offs, csr, wbuf, b2, bufA, N);

    // layer 3
    gemm_mfma_kernel<256, 64, 64, 1><<<dim3(gb64, 1), 256, 0, stream>>>(
        bufA, wt3h, wt3l, va3h, va3l, h16, alpS, alpD, N);
    maxagg1_kernel<false><<<N, 64, 0, stream>>>(h16, alpS, alpD, offs, csr, wbuf, b3, out, N);
}